// Round 1
// baseline (8640.199 us; speedup 1.0000x reference)
//
#include <hip/hip_runtime.h>

typedef unsigned short u16;
typedef unsigned int u32;
typedef float f32x4 __attribute__((ext_vector_type(4)));
typedef __bf16 bf16x8 __attribute__((ext_vector_type(8)));

static constexpr int D = 768, FFD = 3072, SIMC = 192, NH = 8, HD = 96;
static constexpr int B = 128, K = 128, M = B * K, NL = 4;
static constexpr float SCALE_F = 0.10206207261596575f; // 96^-0.5
static constexpr float BOOST_F = 0.3f;
static constexpr float EPS_F = 1e-5f;

__device__ __forceinline__ float bf2f(u16 u) {
  union { u32 i; float f; } v; v.i = ((u32)u) << 16; return v.f;
}
__device__ __forceinline__ u16 f2bf(float f) {
  union { float f; u32 i; } v; v.f = f;
  u32 u = v.i;
  u32 r = (u + 0x7FFFu + ((u >> 16) & 1u)) >> 16;
  return (u16)r;
}

// ---------------- add positional embedding ----------------
__global__ __launch_bounds__(256) void addpos_kernel(
    const float* __restrict__ slots, const float* __restrict__ pos,
    float* __restrict__ x) {
  int i = blockIdx.x * 256 + threadIdx.x;  // < M*D
  int m = i / D;
  int d = i - m * D;
  x[i] = slots[i] + pos[(m & (K - 1)) * D + d];
}

// ---------------- layernorm ----------------
__device__ __forceinline__ float block_sum(float v, float* sbuf) {
#pragma unroll
  for (int off = 32; off > 0; off >>= 1) v += __shfl_xor(v, off, 64);
  int lane = threadIdx.x & 63, w = threadIdx.x >> 6;
  if (lane == 0) sbuf[w] = v;
  __syncthreads();
  v = sbuf[0] + sbuf[1] + sbuf[2] + sbuf[3];
  __syncthreads();
  return v;
}

template <bool OUT_BF16>
__global__ __launch_bounds__(256) void ln_kernel(
    const float* __restrict__ x, const float* __restrict__ g,
    const float* __restrict__ b, void* __restrict__ out) {
  __shared__ float sbuf[4];
  int row = blockIdx.x, tid = threadIdx.x;
  const float* xr = x + (size_t)row * D;
  float v0 = xr[tid], v1 = xr[tid + 256], v2 = xr[tid + 512];
  float s = block_sum(v0 + v1 + v2, sbuf);
  float mean = s * (1.0f / D);
  float d0 = v0 - mean, d1 = v1 - mean, d2 = v2 - mean;
  float sq = block_sum(d0 * d0 + d1 * d1 + d2 * d2, sbuf);
  float rs = rsqrtf(sq * (1.0f / D) + EPS_F);
  float y0 = d0 * rs * g[tid] + b[tid];
  float y1 = d1 * rs * g[tid + 256] + b[tid + 256];
  float y2 = d2 * rs * g[tid + 512] + b[tid + 512];
  if (OUT_BF16) {
    u16* o = (u16*)out + (size_t)row * D;
    o[tid] = f2bf(y0); o[tid + 256] = f2bf(y1); o[tid + 512] = f2bf(y2);
  } else {
    float* o = (float*)out + (size_t)row * D;
    o[tid] = y0; o[tid + 256] = y1; o[tid + 512] = y2;
  }
}

// ---------------- GEMM: C[M,N] = A(bf16)[M,K] @ B(f32->bf16)[K,N] ----------------
// 64x64 tile, BK=32, 4 waves, each wave 32x32 via 2x2 mfma_f32_16x16x32_bf16.
template <bool OUT_BF16, bool BIAS, bool GELU, bool RESID>
__global__ __launch_bounds__(256) void gemm_kernel(
    const u16* __restrict__ A, const float* __restrict__ Bw,
    const float* __restrict__ bias, const float* __restrict__ resid,
    void* __restrict__ Cout, int N, int Kdim) {
  __shared__ u16 lA[64][40];  // row-major [m][k], +8 pad
  __shared__ u16 lB[64][40];  // transposed [n][k], +8 pad
  int tid = threadIdx.x;
  int n0 = blockIdx.x * 64, m0 = blockIdx.y * 64;
  int w = tid >> 6, lane = tid & 63;
  int wr = w >> 1, wc = w & 1;
  int lr = lane & 15, lg = lane >> 4;
  f32x4 acc[2][2] = {};

  int ar = tid >> 2, ak = (tid & 3) * 8;  // A staging: row, k-offset
  int bk = tid >> 3, bn = (tid & 7) * 8;  // B staging: k-row, n-offset
  const u16* Ap = A + (size_t)(m0 + ar) * Kdim + ak;
  const float* Bp = Bw + (size_t)bk * N + n0 + bn;

  for (int kt = 0; kt < Kdim; kt += 32) {
    uint4 av = *(const uint4*)Ap;
    Ap += 32;
    float4 b0 = *(const float4*)Bp;
    float4 b1 = *(const float4*)(Bp + 4);
    Bp += (size_t)32 * N;
    *(uint4*)(&lA[ar][ak]) = av;
    u16 t[8] = {f2bf(b0.x), f2bf(b0.y), f2bf(b0.z), f2bf(b0.w),
                f2bf(b1.x), f2bf(b1.y), f2bf(b1.z), f2bf(b1.w)};
#pragma unroll
    for (int i = 0; i < 8; ++i) lB[bn + i][bk] = t[i];
    __syncthreads();
#pragma unroll
    for (int m = 0; m < 2; ++m) {
      bf16x8 af = *(const bf16x8*)(&lA[32 * wr + 16 * m + lr][8 * lg]);
#pragma unroll
      for (int n = 0; n < 2; ++n) {
        bf16x8 bf = *(const bf16x8*)(&lB[32 * wc + 16 * n + lr][8 * lg]);
        acc[m][n] = __builtin_amdgcn_mfma_f32_16x16x32_bf16(af, bf, acc[m][n], 0, 0, 0);
      }
    }
    __syncthreads();
  }
  // epilogue
#pragma unroll
  for (int m = 0; m < 2; ++m) {
#pragma unroll
    for (int n = 0; n < 2; ++n) {
      int col = n0 + 32 * wc + 16 * n + lr;
#pragma unroll
      for (int r = 0; r < 4; ++r) {
        int row = m0 + 32 * wr + 16 * m + 4 * lg + r;
        float v = acc[m][n][r];
        if (BIAS) v += bias[col];
        if (GELU) v = 0.5f * v * (1.0f + erff(v * 0.70710678118654752f));
        if (RESID) v += resid[(size_t)row * N + col];
        if (OUT_BF16) ((u16*)Cout)[(size_t)row * N + col] = f2bf(v);
        else ((float*)Cout)[(size_t)row * N + col] = v;
      }
    }
  }
}

// ---------------- normalize s rows (192 wide) ----------------
__global__ __launch_bounds__(64) void snorm_kernel(float* __restrict__ s) {
  int row = blockIdx.x, lane = threadIdx.x;
  float* sr = s + (size_t)row * SIMC;
  float v0 = sr[lane], v1 = sr[lane + 64], v2 = sr[lane + 128];
  float sq = v0 * v0 + v1 * v1 + v2 * v2;
#pragma unroll
  for (int off = 32; off > 0; off >>= 1) sq += __shfl_xor(sq, off, 64);
  float inv = 1.0f / fmaxf(sqrtf(sq), 1e-12f);
  sr[lane] = v0 * inv; sr[lane + 64] = v1 * inv; sr[lane + 128] = v2 * inv;
}

// ---------------- sim[b] = s_norm[b] @ s_norm[b]^T ----------------
__global__ __launch_bounds__(256) void sim_kernel(
    const float* __restrict__ s, float* __restrict__ sim) {
  int b = blockIdx.x;
  __shared__ float sl[128][193];
  int tid = threadIdx.x;
  const float* sb = s + (size_t)b * K * SIMC;
  for (int idx = tid; idx < K * SIMC; idx += 256) {
    int r = idx / SIMC, c = idx - r * SIMC;
    sl[r][c] = sb[idx];
  }
  __syncthreads();
  float* simb = sim + (size_t)b * K * K;
  for (int i = 0; i < 64; ++i) {
    int idx = i * 256 + tid;
    int q = idx >> 7, k2 = idx & 127;
    float acc = 0.f;
#pragma unroll 8
    for (int c = 0; c < SIMC; ++c) acc += sl[q][c] * sl[k2][c];
    simb[idx] = acc;
  }
}

// ---------------- attention per (b,h) ----------------
__global__ __launch_bounds__(256) void attn_kernel(
    const u16* __restrict__ qb, const u16* __restrict__ kb,
    const u16* __restrict__ vb, const float* __restrict__ sim,
    u16* __restrict__ ob) {
  int bh = blockIdx.x;
  int b = bh >> 3, h = bh & 7;
  __shared__ float kt[128][HD + 1];
  __shared__ float vt[128][HD + 1];
  __shared__ float qrow[4][HD];
  __shared__ float abuf[4][128];
  int tid = threadIdx.x;
  const size_t base = (size_t)b * K * D + (size_t)h * HD;
  for (int idx = tid; idx < K * HD; idx += 256) {
    int r = idx / HD, d = idx - r * HD;
    kt[r][d] = bf2f(kb[base + (size_t)r * D + d]);
    vt[r][d] = bf2f(vb[base + (size_t)r * D + d]);
  }
  __syncthreads();
  int w = tid >> 6, lane = tid & 63;
  for (int it = 0; it < 32; ++it) {
    int r = it * 4 + w;
    for (int d = lane; d < HD; d += 64) qrow[w][d] = bf2f(qb[base + (size_t)r * D + d]);
    __syncthreads();
    int c0 = lane, c1 = lane + 64;
    float s0 = 0.f, s1 = 0.f;
#pragma unroll 8
    for (int d = 0; d < HD; ++d) {
      float qd = qrow[w][d];
      s0 += qd * kt[c0][d];
      s1 += qd * kt[c1][d];
    }
    const float* simr = sim + ((size_t)b * K + r) * K;
    s0 = s0 * SCALE_F + BOOST_F * simr[c0];
    s1 = s1 * SCALE_F + BOOST_F * simr[c1];
    float mx = fmaxf(s0, s1);
#pragma unroll
    for (int off = 32; off > 0; off >>= 1) mx = fmaxf(mx, __shfl_xor(mx, off, 64));
    float e0 = expf(s0 - mx), e1 = expf(s1 - mx);
    float sum = e0 + e1;
#pragma unroll
    for (int off = 32; off > 0; off >>= 1) sum += __shfl_xor(sum, off, 64);
    float inv = 1.0f / sum;
    abuf[w][c0] = e0 * inv;
    abuf[w][c1] = e1 * inv;
    __syncthreads();
    // PV: o[d] = sum_k a[k] * v[k][d]
    float a0 = 0.f;
    int d0 = lane;
#pragma unroll 8
    for (int kk = 0; kk < K; ++kk) a0 += abuf[w][kk] * vt[kk][d0];
    size_t obase = base + (size_t)r * D;
    ob[obase + d0] = f2bf(a0);
    if (lane < 32) {
      float a1 = 0.f;
      int d1 = lane + 64;
#pragma unroll 8
      for (int kk = 0; kk < K; ++kk) a1 += abuf[w][kk] * vt[kk][d1];
      ob[obase + d1] = f2bf(a1);
    }
    __syncthreads();
  }
}

// ---------------- host ----------------
extern "C" void kernel_launch(void* const* d_in, const int* in_sizes, int n_in,
                              void* d_out, int out_size, void* d_ws, size_t ws_size,
                              hipStream_t stream) {
  (void)in_sizes; (void)n_in; (void)out_size;
  const float* slots = (const float*)d_in[0];
  const float* pos   = (const float*)d_in[1];
  const float* Wq    = (const float*)d_in[2];
  const float* Wk    = (const float*)d_in[3];
  const float* Wv    = (const float*)d_in[4];
  const float* Wo    = (const float*)d_in[5];
  const float* bo    = (const float*)d_in[6];
  const float* Wsim  = (const float*)d_in[7];
  const float* g1    = (const float*)d_in[8];
  const float* b1    = (const float*)d_in[9];
  const float* g2    = (const float*)d_in[10];
  const float* b2    = (const float*)d_in[11];
  const float* Wff1  = (const float*)d_in[12];
  const float* bff1  = (const float*)d_in[13];
  const float* Wff2  = (const float*)d_in[14];
  const float* bff2  = (const float*)d_in[15];
  const float* gf    = (const float*)d_in[16];
  const float* bfin  = (const float*)d_in[17];

  char* p = (char*)d_ws;
  float* x   = (float*)p; p += (size_t)M * D * 4;
  u16*   nx  = (u16*)p;   p += (size_t)M * D * 2;
  u16*   qb  = (u16*)p;   p += (size_t)M * D * 2;
  u16*   kb  = (u16*)p;   p += (size_t)M * D * 2;
  u16*   vb  = (u16*)p;   p += (size_t)M * D * 2;
  float* s   = (float*)p; p += (size_t)M * SIMC * 4;
  float* sim = (float*)p; p += (size_t)B * K * K * 4;
  u16*   ob  = (u16*)p;   p += (size_t)M * D * 2;
  u16*   hb  = (u16*)p;   p += (size_t)4096 * FFD * 2;
  if ((size_t)(p - (char*)d_ws) > ws_size) return;  // ws too small -> clean fail

  addpos_kernel<<<M * D / 256, 256, 0, stream>>>(slots, pos, x);

  dim3 gq(D / 64, M / 64);       // 12 x 256
  dim3 gs(SIMC / 64, M / 64);    // 3 x 256
  dim3 gf1(FFD / 64, 4096 / 64); // 48 x 64
  dim3 gf2(D / 64, 4096 / 64);   // 12 x 64

  for (int l = 0; l < NL; ++l) {
    ln_kernel<true><<<M, 256, 0, stream>>>(x, g1 + l * D, b1 + l * D, nx);
    gemm_kernel<true, false, false, false><<<gq, 256, 0, stream>>>(
        nx, Wq + (size_t)l * D * D, nullptr, nullptr, qb, D, D);
    gemm_kernel<true, false, false, false><<<gq, 256, 0, stream>>>(
        nx, Wk + (size_t)l * D * D, nullptr, nullptr, kb, D, D);
    gemm_kernel<true, false, false, false><<<gq, 256, 0, stream>>>(
        nx, Wv + (size_t)l * D * D, nullptr, nullptr, vb, D, D);
    gemm_kernel<false, false, false, false><<<gs, 256, 0, stream>>>(
        nx, Wsim + (size_t)l * D * SIMC, nullptr, nullptr, s, SIMC, D);
    snorm_kernel<<<M, 64, 0, stream>>>(s);
    sim_kernel<<<B, 256, 0, stream>>>(s, sim);
    attn_kernel<<<B * NH, 256, 0, stream>>>(qb, kb, vb, sim, ob);
    gemm_kernel<false, true, false, true><<<gq, 256, 0, stream>>>(
        ob, Wo + (size_t)l * D * D, bo + l * D, x, x, D, D);
    ln_kernel<true><<<M, 256, 0, stream>>>(x, g2 + l * D, b2 + l * D, nx);
    for (int c = 0; c < 4; ++c) {
      size_t off = (size_t)c * 4096;
      gemm_kernel<true, true, true, false><<<gf1, 256, 0, stream>>>(
          nx + off * D, Wff1 + (size_t)l * D * FFD, bff1 + l * FFD, nullptr,
          hb, FFD, D);
      gemm_kernel<false, true, false, true><<<gf2, 256, 0, stream>>>(
          hb, Wff2 + (size_t)l * FFD * D, bff2 + l * D, x + off * D,
          x + off * D, D, FFD);
    }
  }
  ln_kernel<false><<<M, 256, 0, stream>>>(x, gf, bfin, d_out);
}

// Round 2
// 2359.049 us; speedup vs baseline: 3.6626x; 3.6626x over previous
//
#include <hip/hip_runtime.h>

typedef unsigned short u16;
typedef unsigned int u32;
typedef float f32x4 __attribute__((ext_vector_type(4)));
typedef __bf16 bf16x8 __attribute__((ext_vector_type(8)));

static constexpr int D = 768, FFD = 3072, SIMC = 192, NH = 8, HD = 96;
static constexpr int B = 128, K = 128, M = B * K, NL = 4;
static constexpr int QKVW = 2304;  // fused qkv width
static constexpr float SCALE_F = 0.10206207261596575f;  // 96^-0.5
static constexpr float SQRT_BOOST = 0.5477225575051661f; // sqrt(0.3)
static constexpr float EPS_F = 1e-5f;

__device__ __forceinline__ float bf2f(u16 u) {
  union { u32 i; float f; } v; v.i = ((u32)u) << 16; return v.f;
}
__device__ __forceinline__ u16 f2bf(float f) {
  union { float f; u32 i; } v; v.f = f;
  u32 u = v.i;
  u32 r = (u + 0x7FFFu + ((u >> 16) & 1u)) >> 16;
  return (u16)r;
}

__device__ __forceinline__ void gload16(const void* g, void* l) {
  __builtin_amdgcn_global_load_lds(
      (const __attribute__((address_space(1))) void*)g,
      (__attribute__((address_space(3))) void*)l, 16, 0, 0);
}

// ---------------- add positional embedding ----------------
__global__ __launch_bounds__(256) void addpos_kernel(
    const float* __restrict__ slots, const float* __restrict__ pos,
    float* __restrict__ x) {
  int i = blockIdx.x * 256 + threadIdx.x;
  int m = i / D;
  int d = i - m * D;
  x[i] = slots[i] + pos[(m & (K - 1)) * D + d];
}

// ---------------- layernorm ----------------
__device__ __forceinline__ float block_sum(float v, float* sbuf) {
#pragma unroll
  for (int off = 32; off > 0; off >>= 1) v += __shfl_xor(v, off, 64);
  int lane = threadIdx.x & 63, w = threadIdx.x >> 6;
  if (lane == 0) sbuf[w] = v;
  __syncthreads();
  v = sbuf[0] + sbuf[1] + sbuf[2] + sbuf[3];
  __syncthreads();
  return v;
}

template <bool OUT_BF16>
__global__ __launch_bounds__(256) void ln_kernel(
    const float* __restrict__ x, const float* __restrict__ g,
    const float* __restrict__ b, void* __restrict__ out) {
  __shared__ float sbuf[4];
  int row = blockIdx.x, tid = threadIdx.x;
  const float* xr = x + (size_t)row * D;
  float v0 = xr[tid], v1 = xr[tid + 256], v2 = xr[tid + 512];
  float s = block_sum(v0 + v1 + v2, sbuf);
  float mean = s * (1.0f / D);
  float d0 = v0 - mean, d1 = v1 - mean, d2 = v2 - mean;
  float sq = block_sum(d0 * d0 + d1 * d1 + d2 * d2, sbuf);
  float rs = rsqrtf(sq * (1.0f / D) + EPS_F);
  float y0 = d0 * rs * g[tid] + b[tid];
  float y1 = d1 * rs * g[tid + 256] + b[tid + 256];
  float y2 = d2 * rs * g[tid + 512] + b[tid + 512];
  if (OUT_BF16) {
    u16* o = (u16*)out + (size_t)row * D;
    o[tid] = f2bf(y0); o[tid + 256] = f2bf(y1); o[tid + 512] = f2bf(y2);
  } else {
    float* o = (float*)out + (size_t)row * D;
    o[tid] = y0; o[tid + 256] = y1; o[tid + 512] = y2;
  }
}

// ---------------- weight transpose+convert: W[Kd][N] f32 -> Wt[N][Kd] bf16 ----------------
__global__ __launch_bounds__(256) void wconv_kernel(
    const float* __restrict__ W, u16* __restrict__ Wt, int N, int Kd) {
  __shared__ u16 t[32][33];
  int n0 = blockIdx.x * 32, k0 = blockIdx.y * 32;
  int tid = threadIdx.x;
  int c = tid & 31, r4 = tid >> 5;
#pragma unroll
  for (int i = 0; i < 4; ++i) {
    int r = r4 + i * 8;
    t[r][c] = f2bf(W[(size_t)(k0 + r) * N + n0 + c]);
  }
  __syncthreads();
#pragma unroll
  for (int i = 0; i < 4; ++i) {
    int r = r4 + i * 8;
    Wt[(size_t)(n0 + r) * Kd + k0 + c] = t[c][r];
  }
}

// ---------------- GEMM 128x128 tile, BK=32, global_load_lds (m97-style) ----------------
// C[M,N] = A[M,K](bf16) @ Bt[N,K]^T(bf16)
template <bool OUT_BF16, bool BIAS, bool GELU, bool RESID>
__global__ __launch_bounds__(256) void gemm128_kernel(
    const u16* __restrict__ A, const u16* __restrict__ Bt,
    const float* __restrict__ bias, const float* __restrict__ resid,
    void* __restrict__ Cout, int N, int Kdim, int qcols, float qscale) {
  __shared__ u16 lA[128 * 32];
  __shared__ u16 lB[128 * 32];
  int tid = threadIdx.x;
  int w = tid >> 6, lane = tid & 63;
  int n0 = blockIdx.x * 128, m0 = blockIdx.y * 128;
  int wr = w >> 1, wc = w & 1;
  int lr = lane & 15, lg = lane >> 4;
  f32x4 acc[4][4] = {};

  int srow0 = w * 16 + (lane >> 2);
  int skk = (lane & 3) * 8;
  const u16* Ar0 = A + (size_t)(m0 + srow0) * Kdim + skk;
  const u16* Ar1 = A + (size_t)(m0 + 64 + srow0) * Kdim + skk;
  const u16* Br0 = Bt + (size_t)(n0 + srow0) * Kdim + skk;
  const u16* Br1 = Bt + (size_t)(n0 + 64 + srow0) * Kdim + skk;
  u16* lA0 = lA + w * 512;
  u16* lA1 = lA + 2048 + w * 512;
  u16* lB0 = lB + w * 512;
  u16* lB1 = lB + 2048 + w * 512;

  for (int kt = 0; kt < Kdim; kt += 32) {
    gload16(Ar0 + kt, lA0);
    gload16(Ar1 + kt, lA1);
    gload16(Br0 + kt, lB0);
    gload16(Br1 + kt, lB1);
    __syncthreads();
    bf16x8 af[4], bfr[4];
#pragma unroll
    for (int m = 0; m < 4; ++m)
      af[m] = *(const bf16x8*)(lA + (64 * wr + 16 * m + lr) * 32 + 8 * lg);
#pragma unroll
    for (int n = 0; n < 4; ++n)
      bfr[n] = *(const bf16x8*)(lB + (64 * wc + 16 * n + lr) * 32 + 8 * lg);
#pragma unroll
    for (int m = 0; m < 4; ++m)
#pragma unroll
      for (int n = 0; n < 4; ++n)
        acc[m][n] = __builtin_amdgcn_mfma_f32_16x16x32_bf16(af[m], bfr[n], acc[m][n], 0, 0, 0);
    __syncthreads();
  }
#pragma unroll
  for (int m = 0; m < 4; ++m) {
#pragma unroll
    for (int n = 0; n < 4; ++n) {
      int col = n0 + 64 * wc + 16 * n + lr;
#pragma unroll
      for (int r = 0; r < 4; ++r) {
        int row = m0 + 64 * wr + 16 * m + 4 * lg + r;
        float v = acc[m][n][r];
        if (BIAS) v += bias[col];
        if (GELU) v = 0.5f * v * (1.0f + erff(v * 0.70710678118654752f));
        if (RESID) v += resid[(size_t)row * N + col];
        if (qcols && col < qcols) v *= qscale;
        if (OUT_BF16) ((u16*)Cout)[(size_t)row * N + col] = f2bf(v);
        else ((float*)Cout)[(size_t)row * N + col] = v;
      }
    }
  }
}

// ---------------- old 64-tile GEMM (f32 B on the fly) for sim projection ----------------
__global__ __launch_bounds__(256) void gemm64_kernel(
    const u16* __restrict__ A, const float* __restrict__ Bw,
    float* __restrict__ Cout, int N, int Kdim) {
  __shared__ u16 lA[64][40];
  __shared__ u16 lB[64][40];
  int tid = threadIdx.x;
  int n0 = blockIdx.x * 64, m0 = blockIdx.y * 64;
  int w = tid >> 6, lane = tid & 63;
  int wr = w >> 1, wc = w & 1;
  int lr = lane & 15, lg = lane >> 4;
  f32x4 acc[2][2] = {};
  int ar = tid >> 2, ak = (tid & 3) * 8;
  int bk = tid >> 3, bn = (tid & 7) * 8;
  const u16* Ap = A + (size_t)(m0 + ar) * Kdim + ak;
  const float* Bp = Bw + (size_t)bk * N + n0 + bn;
  for (int kt = 0; kt < Kdim; kt += 32) {
    uint4 av = *(const uint4*)Ap;
    Ap += 32;
    float4 b0 = *(const float4*)Bp;
    float4 b1 = *(const float4*)(Bp + 4);
    Bp += (size_t)32 * N;
    *(uint4*)(&lA[ar][ak]) = av;
    u16 t[8] = {f2bf(b0.x), f2bf(b0.y), f2bf(b0.z), f2bf(b0.w),
                f2bf(b1.x), f2bf(b1.y), f2bf(b1.z), f2bf(b1.w)};
#pragma unroll
    for (int i = 0; i < 8; ++i) lB[bn + i][bk] = t[i];
    __syncthreads();
#pragma unroll
    for (int m = 0; m < 2; ++m) {
      bf16x8 af = *(const bf16x8*)(&lA[32 * wr + 16 * m + lr][8 * lg]);
#pragma unroll
      for (int n = 0; n < 2; ++n) {
        bf16x8 bf = *(const bf16x8*)(&lB[32 * wc + 16 * n + lr][8 * lg]);
        acc[m][n] = __builtin_amdgcn_mfma_f32_16x16x32_bf16(af, bf, acc[m][n], 0, 0, 0);
      }
    }
    __syncthreads();
  }
#pragma unroll
  for (int m = 0; m < 2; ++m)
#pragma unroll
    for (int n = 0; n < 2; ++n) {
      int col = n0 + 32 * wc + 16 * n + lr;
#pragma unroll
      for (int r = 0; r < 4; ++r) {
        int row = m0 + 32 * wr + 16 * m + 4 * lg + r;
        Cout[(size_t)row * N + col] = acc[m][n][r];
      }
    }
}

// ---------------- s-normalize: s_bf = sqrt(BOOST) * s / max(||s||, 1e-12) ----------------
__global__ __launch_bounds__(64) void snorm_kernel(
    const float* __restrict__ s, u16* __restrict__ sbf) {
  int row = blockIdx.x, lane = threadIdx.x;
  const float* sr = s + (size_t)row * SIMC;
  float v0 = sr[lane], v1 = sr[lane + 64], v2 = sr[lane + 128];
  float sq = v0 * v0 + v1 * v1 + v2 * v2;
#pragma unroll
  for (int off = 32; off > 0; off >>= 1) sq += __shfl_xor(sq, off, 64);
  float inv = SQRT_BOOST / fmaxf(sqrtf(sq), 1e-12f);
  u16* o = sbf + (size_t)row * SIMC;
  o[lane] = f2bf(v0 * inv);
  o[lane + 64] = f2bf(v1 * inv);
  o[lane + 128] = f2bf(v2 * inv);
}

// ---------------- MFMA attention: one block per (b,h), 4 waves x 32 q-rows ----------------
// scores = (SCALE*Q)K^T + (sqrtB*s)(sqrtB*s)^T accumulated in one MFMA chain.
__global__ __launch_bounds__(256) void attn_kernel(
    const u16* __restrict__ qkv, const u16* __restrict__ sbf,
    u16* __restrict__ ob) {
  __shared__ u16 Vt[96][136];
  __shared__ u16 Pl[4][32][136];
  int bh = blockIdx.x, b = bh >> 3, h = bh & 7;
  int tid = threadIdx.x, w = tid >> 6, lane = tid & 63;
  int lr = lane & 15, lg = lane >> 4;
  const u16* qb = qkv + (size_t)b * K * QKVW + h * HD;
  const u16* kb = qb + D;
  const u16* vb = qb + 2 * D;
  const u16* sb = sbf + (size_t)b * K * SIMC;
  // stage V transposed
  for (int idx = tid; idx < 128 * 12; idx += 256) {
    int r = idx / 12, db = idx - r * 12;
    uint4 v4 = *(const uint4*)(vb + (size_t)r * QKVW + db * 8);
    u32 vv[4] = {v4.x, v4.y, v4.z, v4.w};
#pragma unroll
    for (int j = 0; j < 4; ++j) {
      Vt[db * 8 + 2 * j][r] = (u16)(vv[j] & 0xffffu);
      Vt[db * 8 + 2 * j + 1][r] = (u16)(vv[j] >> 16);
    }
  }
  int q0 = 32 * w;
  f32x4 accs[2][8] = {};
#pragma unroll
  for (int ks = 0; ks < 3; ++ks) {
    bf16x8 af[2];
#pragma unroll
    for (int m = 0; m < 2; ++m)
      af[m] = *(const bf16x8*)(qb + (size_t)(q0 + 16 * m + lr) * QKVW + ks * 32 + lg * 8);
#pragma unroll
    for (int n = 0; n < 8; ++n) {
      bf16x8 bf = *(const bf16x8*)(kb + (size_t)(16 * n + lr) * QKVW + ks * 32 + lg * 8);
#pragma unroll
      for (int m = 0; m < 2; ++m)
        accs[m][n] = __builtin_amdgcn_mfma_f32_16x16x32_bf16(af[m], bf, accs[m][n], 0, 0, 0);
    }
  }
#pragma unroll
  for (int ks = 0; ks < 6; ++ks) {
    bf16x8 af[2];
#pragma unroll
    for (int m = 0; m < 2; ++m)
      af[m] = *(const bf16x8*)(sb + (size_t)(q0 + 16 * m + lr) * SIMC + ks * 32 + lg * 8);
#pragma unroll
    for (int n = 0; n < 8; ++n) {
      bf16x8 bf = *(const bf16x8*)(sb + (size_t)(16 * n + lr) * SIMC + ks * 32 + lg * 8);
#pragma unroll
      for (int m = 0; m < 2; ++m)
        accs[m][n] = __builtin_amdgcn_mfma_f32_16x16x32_bf16(af[m], bf, accs[m][n], 0, 0, 0);
    }
  }
  // softmax rows, normalize, write P to LDS as bf16
#pragma unroll
  for (int m = 0; m < 2; ++m) {
    float mx[4] = {-3e38f, -3e38f, -3e38f, -3e38f};
#pragma unroll
    for (int n = 0; n < 8; ++n)
#pragma unroll
      for (int r = 0; r < 4; ++r) mx[r] = fmaxf(mx[r], accs[m][n][r]);
#pragma unroll
    for (int r = 0; r < 4; ++r) {
      mx[r] = fmaxf(mx[r], __shfl_xor(mx[r], 1, 64));
      mx[r] = fmaxf(mx[r], __shfl_xor(mx[r], 2, 64));
      mx[r] = fmaxf(mx[r], __shfl_xor(mx[r], 4, 64));
      mx[r] = fmaxf(mx[r], __shfl_xor(mx[r], 8, 64));
    }
    float sm[4] = {0.f, 0.f, 0.f, 0.f};
#pragma unroll
    for (int n = 0; n < 8; ++n)
#pragma unroll
      for (int r = 0; r < 4; ++r) {
        float e = expf(accs[m][n][r] - mx[r]);
        accs[m][n][r] = e;
        sm[r] += e;
      }
#pragma unroll
    for (int r = 0; r < 4; ++r) {
      sm[r] += __shfl_xor(sm[r], 1, 64);
      sm[r] += __shfl_xor(sm[r], 2, 64);
      sm[r] += __shfl_xor(sm[r], 4, 64);
      sm[r] += __shfl_xor(sm[r], 8, 64);
    }
    float inv[4];
#pragma unroll
    for (int r = 0; r < 4; ++r) inv[r] = 1.0f / sm[r];
#pragma unroll
    for (int n = 0; n < 8; ++n)
#pragma unroll
      for (int r = 0; r < 4; ++r)
        Pl[w][16 * m + 4 * lg + r][16 * n + lr] = f2bf(accs[m][n][r] * inv[r]);
  }
  __syncthreads();
  // PV
  f32x4 acco[2][6] = {};
#pragma unroll
  for (int ks = 0; ks < 4; ++ks) {
    bf16x8 pa[2];
#pragma unroll
    for (int m = 0; m < 2; ++m)
      pa[m] = *(const bf16x8*)(&Pl[w][16 * m + lr][ks * 32 + lg * 8]);
#pragma unroll
    for (int n = 0; n < 6; ++n) {
      bf16x8 bv = *(const bf16x8*)(&Vt[16 * n + lr][ks * 32 + lg * 8]);
#pragma unroll
      for (int m = 0; m < 2; ++m)
        acco[m][n] = __builtin_amdgcn_mfma_f32_16x16x32_bf16(pa[m], bv, acco[m][n], 0, 0, 0);
    }
  }
  u16* obb = ob + (size_t)b * K * D + h * HD;
#pragma unroll
  for (int m = 0; m < 2; ++m)
#pragma unroll
    for (int n = 0; n < 6; ++n)
#pragma unroll
      for (int r = 0; r < 4; ++r)
        obb[(size_t)(q0 + 16 * m + 4 * lg + r) * D + 16 * n + lr] = f2bf(acco[m][n][r]);
}

// ---------------- host ----------------
extern "C" void kernel_launch(void* const* d_in, const int* in_sizes, int n_in,
                              void* d_out, int out_size, void* d_ws, size_t ws_size,
                              hipStream_t stream) {
  (void)in_sizes; (void)n_in; (void)out_size;
  const float* slots = (const float*)d_in[0];
  const float* pos   = (const float*)d_in[1];
  const float* Wq    = (const float*)d_in[2];
  const float* Wk    = (const float*)d_in[3];
  const float* Wv    = (const float*)d_in[4];
  const float* Wo    = (const float*)d_in[5];
  const float* bo    = (const float*)d_in[6];
  const float* Wsim  = (const float*)d_in[7];
  const float* g1    = (const float*)d_in[8];
  const float* b1    = (const float*)d_in[9];
  const float* g2    = (const float*)d_in[10];
  const float* b2    = (const float*)d_in[11];
  const float* Wff1  = (const float*)d_in[12];
  const float* bff1  = (const float*)d_in[13];
  const float* Wff2  = (const float*)d_in[14];
  const float* bff2  = (const float*)d_in[15];
  const float* gf    = (const float*)d_in[16];
  const float* bfin  = (const float*)d_in[17];

  char* p = (char*)d_ws;
  float* x    = (float*)p; p += (size_t)M * D * 4;
  u16*   nx   = (u16*)p;   p += (size_t)M * D * 2;
  u16*   qkvb = (u16*)p;   p += (size_t)M * QKVW * 2;
  u16*   ob   = (u16*)p;   p += (size_t)M * D * 2;
  float* s    = (float*)p; p += (size_t)M * SIMC * 4;
  u16*   sbf  = (u16*)p;   p += (size_t)M * SIMC * 2;
  if ((size_t)(p - (char*)d_ws) > ws_size) return;
  // aliases (stream-ordered liveness, see layer schedule)
  u16* wtA = ob;                       // [2304][768] qkv weights^T
  u16* wtB = (u16*)s;                  // [768][768]  Wo^T
  u16* wtC = wtB + 768 * 768;          // [3072][768] Wff1^T
  u16* wtD = wtC + 3072 * 768;         // [768][3072] Wff2^T
  u16* hb  = qkvb;                     // [M][3072] ffn hidden (spans qkvb+ob)

  addpos_kernel<<<M * D / 256, 256, 0, stream>>>(slots, pos, x);

  dim3 gw(24, 24);                 // 768x768 transpose
  dim3 gw1(96, 24);                // 768x3072 -> [3072][768]
  dim3 gw2(24, 96);                // 3072x768 -> [768][3072]
  dim3 gqkv(QKVW / 128, M / 128);  // 18 x 128
  dim3 go(D / 128, M / 128);       // 6 x 128
  dim3 gf1(FFD / 128, M / 128);    // 24 x 128
  dim3 gsim(SIMC / 64, M / 64);    // 3 x 256

  for (int l = 0; l < NL; ++l) {
    ln_kernel<true><<<M, 256, 0, stream>>>(x, g1 + l * D, b1 + l * D, nx);
    wconv_kernel<<<gw, 256, 0, stream>>>(Wq + (size_t)l * D * D, wtA, D, D);
    wconv_kernel<<<gw, 256, 0, stream>>>(Wk + (size_t)l * D * D, wtA + 768 * 768, D, D);
    wconv_kernel<<<gw, 256, 0, stream>>>(Wv + (size_t)l * D * D, wtA + 2 * 768 * 768, D, D);
    gemm128_kernel<true, false, false, false><<<gqkv, 256, 0, stream>>>(
        nx, wtA, nullptr, nullptr, qkvb, QKVW, D, D, SCALE_F);
    gemm64_kernel<<<gsim, 256, 0, stream>>>(
        nx, Wsim + (size_t)l * D * SIMC, s, SIMC, D);
    snorm_kernel<<<M, 64, 0, stream>>>(s, sbf);
    wconv_kernel<<<gw, 256, 0, stream>>>(Wo + (size_t)l * D * D, wtB, D, D);
    wconv_kernel<<<gw1, 256, 0, stream>>>(Wff1 + (size_t)l * D * FFD, wtC, FFD, D);
    wconv_kernel<<<gw2, 256, 0, stream>>>(Wff2 + (size_t)l * FFD * D, wtD, D, FFD);
    attn_kernel<<<B * NH, 256, 0, stream>>>(qkvb, sbf, ob);
    gemm128_kernel<false, true, false, true><<<go, 256, 0, stream>>>(
        ob, wtB, bo + l * D, x, x, D, D, 0, 1.0f);
    ln_kernel<true><<<M, 256, 0, stream>>>(x, g2 + l * D, b2 + l * D, nx);
    gemm128_kernel<true, true, true, false><<<gf1, 256, 0, stream>>>(
        nx, wtC, bff1 + l * FFD, nullptr, hb, FFD, D, 0, 1.0f);
    gemm128_kernel<false, true, false, true><<<go, 256, 0, stream>>>(
        hb, wtD, bff2 + l * D, x, x, D, FFD, 0, 1.0f);
  }
  ln_kernel<false><<<M, 256, 0, stream>>>(x, gf, bfin, d_out);
}

// Round 3
// 1871.829 us; speedup vs baseline: 4.6159x; 1.2603x over previous
//
#include <hip/hip_runtime.h>

typedef unsigned short u16;
typedef unsigned int u32;
typedef float f32x4 __attribute__((ext_vector_type(4)));
typedef __bf16 bf16x8 __attribute__((ext_vector_type(8)));

static constexpr int D = 768, FFD = 3072, SIMC = 192, NH = 8, HD = 96;
static constexpr int B = 128, K = 128, M = B * K, NL = 4;
static constexpr int QKVW = 2304;  // fused qkv width
static constexpr float SCALE_F = 0.10206207261596575f;  // 96^-0.5
static constexpr float SQRT_BOOST = 0.5477225575051661f; // sqrt(0.3)
static constexpr float EPS_F = 1e-5f;

__device__ __forceinline__ float bf2f(u16 u) {
  union { u32 i; float f; } v; v.i = ((u32)u) << 16; return v.f;
}
__device__ __forceinline__ u16 f2bf(float f) {
  union { float f; u32 i; } v; v.f = f;
  u32 u = v.i;
  u32 r = (u + 0x7FFFu + ((u >> 16) & 1u)) >> 16;
  return (u16)r;
}

__device__ __forceinline__ void gload16(const void* g, void* l) {
  __builtin_amdgcn_global_load_lds(
      (const __attribute__((address_space(1))) void*)g,
      (__attribute__((address_space(3))) void*)l, 16, 0, 0);
}

// ---------------- add positional embedding ----------------
__global__ __launch_bounds__(256) void addpos_kernel(
    const float* __restrict__ slots, const float* __restrict__ pos,
    float* __restrict__ x) {
  int i = blockIdx.x * 256 + threadIdx.x;
  int m = i / D;
  int d = i - m * D;
  x[i] = slots[i] + pos[(m & (K - 1)) * D + d];
}

// ---------------- layernorm ----------------
__device__ __forceinline__ float block_sum(float v, float* sbuf) {
#pragma unroll
  for (int off = 32; off > 0; off >>= 1) v += __shfl_xor(v, off, 64);
  int lane = threadIdx.x & 63, w = threadIdx.x >> 6;
  if (lane == 0) sbuf[w] = v;
  __syncthreads();
  v = sbuf[0] + sbuf[1] + sbuf[2] + sbuf[3];
  __syncthreads();
  return v;
}

template <bool OUT_BF16>
__global__ __launch_bounds__(256) void ln_kernel(
    const float* __restrict__ x, const float* __restrict__ g,
    const float* __restrict__ b, void* __restrict__ out) {
  __shared__ float sbuf[4];
  int row = blockIdx.x, tid = threadIdx.x;
  const float* xr = x + (size_t)row * D;
  float v0 = xr[tid], v1 = xr[tid + 256], v2 = xr[tid + 512];
  float s = block_sum(v0 + v1 + v2, sbuf);
  float mean = s * (1.0f / D);
  float d0 = v0 - mean, d1 = v1 - mean, d2 = v2 - mean;
  float sq = block_sum(d0 * d0 + d1 * d1 + d2 * d2, sbuf);
  float rs = rsqrtf(sq * (1.0f / D) + EPS_F);
  float y0 = d0 * rs * g[tid] + b[tid];
  float y1 = d1 * rs * g[tid + 256] + b[tid + 256];
  float y2 = d2 * rs * g[tid + 512] + b[tid + 512];
  if (OUT_BF16) {
    u16* o = (u16*)out + (size_t)row * D;
    o[tid] = f2bf(y0); o[tid + 256] = f2bf(y1); o[tid + 512] = f2bf(y2);
  } else {
    float* o = (float*)out + (size_t)row * D;
    o[tid] = y0; o[tid + 256] = y1; o[tid + 512] = y2;
  }
}

// ---------------- weight transpose+convert: W[Kd][N] f32 -> Wt[N][Kd] bf16 ----------------
__global__ __launch_bounds__(256) void wconv_kernel(
    const float* __restrict__ W, u16* __restrict__ Wt, int N, int Kd) {
  __shared__ u16 t[32][33];
  int n0 = blockIdx.x * 32, k0 = blockIdx.y * 32;
  int tid = threadIdx.x;
  int c = tid & 31, r4 = tid >> 5;
#pragma unroll
  for (int i = 0; i < 4; ++i) {
    int r = r4 + i * 8;
    t[r][c] = f2bf(W[(size_t)(k0 + r) * N + n0 + c]);
  }
  __syncthreads();
#pragma unroll
  for (int i = 0; i < 4; ++i) {
    int r = r4 + i * 8;
    Wt[(size_t)(n0 + r) * Kd + k0 + c] = t[c][r];
  }
}

// ===================== 256x256 8-phase GEMM (m201-style, plain HIP) =====================
// C[M,N] = A[M,K](bf16) @ Bt[N,K]^T(bf16).  512 thr = 8 waves (2M x 4N),
// BK=64, LDS 128KB = 2 K-tile buffers x (A,B) x 32KB. XOR swizzle: 16B-unit
// index ^= (row&7), applied on pre-swizzled global source (linear gload_lds
// dest) and on ds_read address (same involution, rule 21).
//
// Phase plan per K-tile (B frags all-resident, A frags per-mseg):
//  p1: readA(ms0,8) readB(ns0,4)  p2: readB(ns1,4)  p3: readA(ms1,8)  p4: -
//  MFMA quadrants: p1:(ms0,ns0) p2:(ms0,ns1) p3:(ms1,ns0) p4:(ms1,ns1)
// Liveness (reads of tile in buf): A-halves done after p3, B-halves after p2.
// Stage schedule (1 half-tile = 2 gload16/thread per phase):
//  p1:buf1.A0(t1) p2:buf1.A1(t1) p3:buf0.B0(t2) p4:buf0.B1(t2)
//  p5:buf0.A0(t2) p6:buf0.A1(t2) p7:buf1.B0(t3) p8:buf1.B1(t3)
// Every stage's target region last-read >=1 phase before issue (barrier-
// ordered). vmcnt(4) at p4/p8 end: keeps newest 4 (last 2 staging phases),
// guarantees everything needed by the next 4 consume-phases has landed.
// Last iteration: stages of t2/t3 skipped; p4 drains vmcnt(0).
template <bool OUT_BF16, bool BIAS, bool GELU_, bool RESID>
__global__ __launch_bounds__(512) void gemm256_kernel(
    const u16* __restrict__ A, const u16* __restrict__ Bt,
    const float* __restrict__ bias, const float* __restrict__ resid,
    void* __restrict__ Cout, int N, int Kdim, int qcols, float qscale, int NBX) {
  __shared__ u16 lds[65536];  // buf0.A | buf0.B | buf1.A | buf1.B (16384 u16 each)
  int tid = threadIdx.x;
  int w = tid >> 6, lane = tid & 63;
  int wm = w >> 2, wn = w & 3;
  int lr = lane & 15, lg = lane >> 4;

  // XCD-bijective swizzle (all our grids divisible by 8)
  int nwg = gridDim.x;
  int cpx = nwg >> 3;
  int swz = (blockIdx.x & 7) * cpx + (blockIdx.x >> 3);
  int bx = swz % NBX, by = swz / NBX;
  int n0 = bx << 8, m0 = by << 8;

  // staging per-thread constants
  int scol = ((lane & 7) ^ (lane >> 3)) << 3;  // pre-swizzled source col-block
  size_t aOff = (size_t)((w << 4) + (lane >> 3)) * Kdim + scol;
  u16* ldsU = lds;

  auto stageA = [&](int buf, int h, int t) {
    const u16* g = A + (size_t)(m0 + (h << 7)) * Kdim + ((size_t)t << 6) + aOff;
    u16* l = ldsU + buf * 32768 + h * 8192 + (w << 10);
    gload16(g, l);
    gload16(g + ((size_t)Kdim << 3), l + 512);
  };
  auto stageB = [&](int buf, int h, int t) {
    const u16* g = Bt + (size_t)(n0 + (h << 7)) * Kdim + ((size_t)t << 6) + aOff;
    u16* l = ldsU + buf * 32768 + 16384 + h * 8192 + (w << 10);
    gload16(g, l);
    gload16(g + ((size_t)Kdim << 3), l + 512);
  };

  // fragment read bases (u16 units); row stride in LDS = 64 u16 (128B)
  const u16* lA0p = ldsU;
  const u16* lB0p = ldsU + 16384;
  const u16* lA1p = ldsU + 32768;
  const u16* lB1p = ldsU + 49152;
  int arow = (wm * 128 + lr) * 64;
  int brow = (wn * 64 + lr) * 64;
  int swz0 = (((lg * 16)) ^ ((lr & 7) << 4)) >> 1;       // ksub 0
  int swz1 = ((64 + lg * 16) ^ ((lr & 7) << 4)) >> 1;    // ksub 1

  f32x4 acc[8][4] = {};
  bf16x8 ar[2][4], br[2][4];

#define READ_A(BASE, MSEG)                                                   \
  do {                                                                       \
    _Pragma("unroll") for (int mm = 0; mm < 4; ++mm) {                       \
      const u16* p_ = (BASE) + arow + ((MSEG) * 64 + mm * 16) * 64;          \
      ar[0][mm] = *(const bf16x8*)(p_ + swz0);                               \
      ar[1][mm] = *(const bf16x8*)(p_ + swz1);                               \
    }                                                                        \
  } while (0)
#define READ_B(BASE, NSEG)                                                   \
  do {                                                                       \
    _Pragma("unroll") for (int nn = 0; nn < 2; ++nn) {                       \
      const u16* p_ = (BASE) + brow + ((NSEG) * 32 + nn * 16) * 64;          \
      br[0][(NSEG) * 2 + nn] = *(const bf16x8*)(p_ + swz0);                  \
      br[1][(NSEG) * 2 + nn] = *(const bf16x8*)(p_ + swz1);                  \
    }                                                                        \
  } while (0)
#define MFMA_Q(MSEG, NSEG)                                                   \
  do {                                                                       \
    __builtin_amdgcn_s_setprio(1);                                           \
    _Pragma("unroll") for (int ks = 0; ks < 2; ++ks)                         \
      _Pragma("unroll") for (int mm = 0; mm < 4; ++mm)                       \
        _Pragma("unroll") for (int nn = 0; nn < 2; ++nn)                     \
          acc[(MSEG) * 4 + mm][(NSEG) * 2 + nn] =                            \
              __builtin_amdgcn_mfma_f32_16x16x32_bf16(                       \
                  ar[ks][mm], br[ks][(NSEG) * 2 + nn],                       \
                  acc[(MSEG) * 4 + mm][(NSEG) * 2 + nn], 0, 0, 0);           \
    __builtin_amdgcn_s_setprio(0);                                           \
  } while (0)
#define SYNC_MID()                                                           \
  do {                                                                       \
    __builtin_amdgcn_sched_barrier(0);                                       \
    __builtin_amdgcn_s_barrier();                                            \
    asm volatile("s_waitcnt lgkmcnt(0)" ::: "memory");                       \
    __builtin_amdgcn_sched_barrier(0);                                       \
  } while (0)
#define SYNC_END()                                                           \
  do {                                                                       \
    __builtin_amdgcn_sched_barrier(0);                                       \
    __builtin_amdgcn_s_barrier();                                            \
    __builtin_amdgcn_sched_barrier(0);                                       \
  } while (0)

  int NK = Kdim >> 6, NI = NK >> 1;
  // ---- prologue: tile0 -> buf0 (all 4 halves), tile1 B -> buf1 ----
  stageA(0, 0, 0); stageA(0, 1, 0); stageB(0, 0, 0); stageB(0, 1, 0);
  stageB(1, 0, 1); stageB(1, 1, 1);
  asm volatile("s_waitcnt vmcnt(4)" ::: "memory");  // tile0 (oldest 8) landed
  __builtin_amdgcn_s_barrier();
  __builtin_amdgcn_sched_barrier(0);

  for (int i = 0; i < NI; ++i) {
    int t1 = 2 * i + 1, t2 = 2 * i + 2, t3 = 2 * i + 3;
    bool last = (i == NI - 1);
    // ---- p1 ----
    READ_A(lA0p, 0); READ_B(lB0p, 0);
    stageA(1, 0, t1);
    SYNC_MID(); MFMA_Q(0, 0); SYNC_END();
    // ---- p2 ----
    READ_B(lB0p, 1);
    stageA(1, 1, t1);
    SYNC_MID(); MFMA_Q(0, 1); SYNC_END();
    // ---- p3 ----
    READ_A(lA0p, 1);
    if (!last) stageB(0, 0, t2);
    SYNC_MID(); MFMA_Q(1, 0); SYNC_END();
    // ---- p4 ----
    if (!last) stageB(0, 1, t2);
    SYNC_MID(); MFMA_Q(1, 1);
    __builtin_amdgcn_sched_barrier(0);
    if (last) asm volatile("s_waitcnt vmcnt(0)" ::: "memory");
    else      asm volatile("s_waitcnt vmcnt(4)" ::: "memory");
    SYNC_END();
    // ---- p5 ----
    READ_A(lA1p, 0); READ_B(lB1p, 0);
    if (!last) stageA(0, 0, t2);
    SYNC_MID(); MFMA_Q(0, 0); SYNC_END();
    // ---- p6 ----
    READ_B(lB1p, 1);
    if (!last) stageA(0, 1, t2);
    SYNC_MID(); MFMA_Q(0, 1); SYNC_END();
    // ---- p7 ----
    READ_A(lA1p, 1);
    if (!last) stageB(1, 0, t3);
    SYNC_MID(); MFMA_Q(1, 0); SYNC_END();
    // ---- p8 ----
    if (!last) stageB(1, 1, t3);
    SYNC_MID(); MFMA_Q(1, 1);
    __builtin_amdgcn_sched_barrier(0);
    if (!last) asm volatile("s_waitcnt vmcnt(4)" ::: "memory");
    SYNC_END();
  }

  // ---- epilogue ----
#pragma unroll
  for (int m = 0; m < 8; ++m) {
#pragma unroll
    for (int n = 0; n < 4; ++n) {
      int col = n0 + wn * 64 + n * 16 + lr;
#pragma unroll
      for (int r = 0; r < 4; ++r) {
        int row = m0 + wm * 128 + m * 16 + lg * 4 + r;
        float v = acc[m][n][r];
        if (BIAS) v += bias[col];
        if (GELU_) v = 0.5f * v * (1.0f + erff(v * 0.70710678118654752f));
        if (RESID) v += resid[(size_t)row * N + col];
        if (qcols && col < qcols) v *= qscale;
        if (OUT_BF16) ((u16*)Cout)[(size_t)row * N + col] = f2bf(v);
        else ((float*)Cout)[(size_t)row * N + col] = v;
      }
    }
  }
#undef READ_A
#undef READ_B
#undef MFMA_Q
#undef SYNC_MID
#undef SYNC_END
}

// ---------------- 64-tile GEMM (f32 B on the fly) for sim projection ----------------
__global__ __launch_bounds__(256) void gemm64_kernel(
    const u16* __restrict__ A, const float* __restrict__ Bw,
    float* __restrict__ Cout, int N, int Kdim) {
  __shared__ u16 lA[64][40];
  __shared__ u16 lB[64][40];
  int tid = threadIdx.x;
  int n0 = blockIdx.x * 64, m0 = blockIdx.y * 64;
  int w = tid >> 6, lane = tid & 63;
  int wr = w >> 1, wc = w & 1;
  int lr = lane & 15, lg = lane >> 4;
  f32x4 acc[2][2] = {};
  int ar = tid >> 2, ak = (tid & 3) * 8;
  int bk = tid >> 3, bn = (tid & 7) * 8;
  const u16* Ap = A + (size_t)(m0 + ar) * Kdim + ak;
  const float* Bp = Bw + (size_t)bk * N + n0 + bn;
  for (int kt = 0; kt < Kdim; kt += 32) {
    uint4 av = *(const uint4*)Ap;
    Ap += 32;
    float4 b0 = *(const float4*)Bp;
    float4 b1 = *(const float4*)(Bp + 4);
    Bp += (size_t)32 * N;
    *(uint4*)(&lA[ar][ak]) = av;
    u16 t[8] = {f2bf(b0.x), f2bf(b0.y), f2bf(b0.z), f2bf(b0.w),
                f2bf(b1.x), f2bf(b1.y), f2bf(b1.z), f2bf(b1.w)};
#pragma unroll
    for (int i = 0; i < 8; ++i) lB[bn + i][bk] = t[i];
    __syncthreads();
#pragma unroll
    for (int m = 0; m < 2; ++m) {
      bf16x8 af = *(const bf16x8*)(&lA[32 * wr + 16 * m + lr][8 * lg]);
#pragma unroll
      for (int n = 0; n < 2; ++n) {
        bf16x8 bf = *(const bf16x8*)(&lB[32 * wc + 16 * n + lr][8 * lg]);
        acc[m][n] = __builtin_amdgcn_mfma_f32_16x16x32_bf16(af, bf, acc[m][n], 0, 0, 0);
      }
    }
    __syncthreads();
  }
#pragma unroll
  for (int m = 0; m < 2; ++m)
#pragma unroll
    for (int n = 0; n < 2; ++n) {
      int col = n0 + 32 * wc + 16 * n + lr;
#pragma unroll
      for (int r = 0; r < 4; ++r) {
        int row = m0 + 32 * wr + 16 * m + 4 * lg + r;
        Cout[(size_t)row * N + col] = acc[m][n][r];
      }
    }
}

// ---------------- s-normalize: s_bf = sqrt(BOOST) * s / max(||s||, 1e-12) ----------------
__global__ __launch_bounds__(64) void snorm_kernel(
    const float* __restrict__ s, u16* __restrict__ sbf) {
  int row = blockIdx.x, lane = threadIdx.x;
  const float* sr = s + (size_t)row * SIMC;
  float v0 = sr[lane], v1 = sr[lane + 64], v2 = sr[lane + 128];
  float sq = v0 * v0 + v1 * v1 + v2 * v2;
#pragma unroll
  for (int off = 32; off > 0; off >>= 1) sq += __shfl_xor(sq, off, 64);
  float inv = SQRT_BOOST / fmaxf(sqrtf(sq), 1e-12f);
  u16* o = sbf + (size_t)row * SIMC;
  o[lane] = f2bf(v0 * inv);
  o[lane + 64] = f2bf(v1 * inv);
  o[lane + 128] = f2bf(v2 * inv);
}

// ---------------- MFMA attention: one block per (b,h), 4 waves x 32 q-rows ----------------
__global__ __launch_bounds__(256) void attn_kernel(
    const u16* __restrict__ qkv, const u16* __restrict__ sbf,
    u16* __restrict__ ob) {
  __shared__ u16 Vt[96][136];
  __shared__ u16 Pl[4][32][136];
  int bh = blockIdx.x, b = bh >> 3, h = bh & 7;
  int tid = threadIdx.x, w = tid >> 6, lane = tid & 63;
  int lr = lane & 15, lg = lane >> 4;
  const u16* qb = qkv + (size_t)b * K * QKVW + h * HD;
  const u16* kb = qb + D;
  const u16* vb = qb + 2 * D;
  const u16* sb = sbf + (size_t)b * K * SIMC;
  for (int idx = tid; idx < 128 * 12; idx += 256) {
    int r = idx / 12, db = idx - r * 12;
    uint4 v4 = *(const uint4*)(vb + (size_t)r * QKVW + db * 8);
    u32 vv[4] = {v4.x, v4.y, v4.z, v4.w};
#pragma unroll
    for (int j = 0; j < 4; ++j) {
      Vt[db * 8 + 2 * j][r] = (u16)(vv[j] & 0xffffu);
      Vt[db * 8 + 2 * j + 1][r] = (u16)(vv[j] >> 16);
    }
  }
  int q0 = 32 * w;
  f32x4 accs[2][8] = {};
#pragma unroll
  for (int ks = 0; ks < 3; ++ks) {
    bf16x8 af[2];
#pragma unroll
    for (int m = 0; m < 2; ++m)
      af[m] = *(const bf16x8*)(qb + (size_t)(q0 + 16 * m + lr) * QKVW + ks * 32 + lg * 8);
#pragma unroll
    for (int n = 0; n < 8; ++n) {
      bf16x8 bf = *(const bf16x8*)(kb + (size_t)(16 * n + lr) * QKVW + ks * 32 + lg * 8);
#pragma unroll
      for (int m = 0; m < 2; ++m)
        accs[m][n] = __builtin_amdgcn_mfma_f32_16x16x32_bf16(af[m], bf, accs[m][n], 0, 0, 0);
    }
  }
#pragma unroll
  for (int ks = 0; ks < 6; ++ks) {
    bf16x8 af[2];
#pragma unroll
    for (int m = 0; m < 2; ++m)
      af[m] = *(const bf16x8*)(sb + (size_t)(q0 + 16 * m + lr) * SIMC + ks * 32 + lg * 8);
#pragma unroll
    for (int n = 0; n < 8; ++n) {
      bf16x8 bf = *(const bf16x8*)(sb + (size_t)(16 * n + lr) * SIMC + ks * 32 + lg * 8);
#pragma unroll
      for (int m = 0; m < 2; ++m)
        accs[m][n] = __builtin_amdgcn_mfma_f32_16x16x32_bf16(af[m], bf, accs[m][n], 0, 0, 0);
    }
  }
#pragma unroll
  for (int m = 0; m < 2; ++m) {
    float mx[4] = {-3e38f, -3e38f, -3e38f, -3e38f};
#pragma unroll
    for (int n = 0; n < 8; ++n)
#pragma unroll
      for (int r = 0; r < 4; ++r) mx[r] = fmaxf(mx[r], accs[m][n][r]);
#pragma unroll
    for (int r = 0; r < 4; ++r) {
      mx[r] = fmaxf(mx[r], __shfl_xor(mx[r], 1, 64));
      mx[r] = fmaxf(mx[r], __shfl_xor(mx[r], 2, 64));
      mx[r] = fmaxf(mx[r], __shfl_xor(mx[r], 4, 64));
      mx[r] = fmaxf(mx[r], __shfl_xor(mx[r], 8, 64));
    }
    float sm[4] = {0.f, 0.f, 0.f, 0.f};
#pragma unroll
    for (int n = 0; n < 8; ++n)
#pragma unroll
      for (int r = 0; r < 4; ++r) {
        float e = expf(accs[m][n][r] - mx[r]);
        accs[m][n][r] = e;
        sm[r] += e;
      }
#pragma unroll
    for (int r = 0; r < 4; ++r) {
      sm[r] += __shfl_xor(sm[r], 1, 64);
      sm[r] += __shfl_xor(sm[r], 2, 64);
      sm[r] += __shfl_xor(sm[r], 4, 64);
      sm[r] += __shfl_xor(sm[r], 8, 64);
    }
    float inv[4];
#pragma unroll
    for (int r = 0; r < 4; ++r) inv[r] = 1.0f / sm[r];
#pragma unroll
    for (int n = 0; n < 8; ++n)
#pragma unroll
      for (int r = 0; r < 4; ++r)
        Pl[w][16 * m + 4 * lg + r][16 * n + lr] = f2bf(accs[m][n][r] * inv[r]);
  }
  __syncthreads();
  f32x4 acco[2][6] = {};
#pragma unroll
  for (int ks = 0; ks < 4; ++ks) {
    bf16x8 pa[2];
#pragma unroll
    for (int m = 0; m < 2; ++m)
      pa[m] = *(const bf16x8*)(&Pl[w][16 * m + lr][ks * 32 + lg * 8]);
#pragma unroll
    for (int n = 0; n < 6; ++n) {
      bf16x8 bv = *(const bf16x8*)(&Vt[16 * n + lr][ks * 32 + lg * 8]);
#pragma unroll
      for (int m = 0; m < 2; ++m)
        acco[m][n] = __builtin_amdgcn_mfma_f32_16x16x32_bf16(pa[m], bv, acco[m][n], 0, 0, 0);
    }
  }
  u16* obb = ob + (size_t)b * K * D + h * HD;
#pragma unroll
  for (int m = 0; m < 2; ++m)
#pragma unroll
    for (int n = 0; n < 6; ++n)
#pragma unroll
      for (int r = 0; r < 4; ++r)
        obb[(size_t)(q0 + 16 * m + 4 * lg + r) * D + 16 * n + lr] = f2bf(acco[m][n][r]);
}

// ---------------- host ----------------
extern "C" void kernel_launch(void* const* d_in, const int* in_sizes, int n_in,
                              void* d_out, int out_size, void* d_ws, size_t ws_size,
                              hipStream_t stream) {
  (void)in_sizes; (void)n_in; (void)out_size;
  const float* slots = (const float*)d_in[0];
  const float* pos   = (const float*)d_in[1];
  const float* Wq    = (const float*)d_in[2];
  const float* Wk    = (const float*)d_in[3];
  const float* Wv    = (const float*)d_in[4];
  const float* Wo    = (const float*)d_in[5];
  const float* bo    = (const float*)d_in[6];
  const float* Wsim  = (const float*)d_in[7];
  const float* g1    = (const float*)d_in[8];
  const float* b1    = (const float*)d_in[9];
  const float* g2    = (const float*)d_in[10];
  const float* b2    = (const float*)d_in[11];
  const float* Wff1  = (const float*)d_in[12];
  const float* bff1  = (const float*)d_in[13];
  const float* Wff2  = (const float*)d_in[14];
  const float* bff2  = (const float*)d_in[15];
  const float* gf    = (const float*)d_in[16];
  const float* bfin  = (const float*)d_in[17];

  char* p = (char*)d_ws;
  float* x    = (float*)p; p += (size_t)M * D * 4;
  u16*   nx   = (u16*)p;   p += (size_t)M * D * 2;
  u16*   qkvb = (u16*)p;   p += (size_t)M * QKVW * 2;
  u16*   ob   = (u16*)p;   p += (size_t)M * D * 2;
  float* s    = (float*)p; p += (size_t)M * SIMC * 4;
  u16*   sbf  = (u16*)p;   p += (size_t)M * SIMC * 2;
  if ((size_t)(p - (char*)d_ws) > ws_size) return;
  u16* wtA = ob;                       // [2304][768] qkv weights^T
  u16* wtB = (u16*)s;                  // [768][768]  Wo^T
  u16* wtC = wtB + 768 * 768;          // [3072][768] Wff1^T
  u16* wtD = wtC + 3072 * 768;         // [768][3072] Wff2^T
  u16* hb  = qkvb;                     // [M][3072] ffn hidden (spans qkvb+ob)

  addpos_kernel<<<M * D / 256, 256, 0, stream>>>(slots, pos, x);

  dim3 gw(24, 24);
  dim3 gw1(96, 24);
  dim3 gw2(24, 96);
  dim3 gsim(SIMC / 64, M / 64);
  int nbx_qkv = QKVW / 256, nwg_qkv = nbx_qkv * (M / 256);  // 9 x 64 = 576
  int nbx_o   = D / 256,    nwg_o   = nbx_o * (M / 256);    // 3 x 64 = 192
  int nbx_f1  = FFD / 256,  nwg_f1  = nbx_f1 * (M / 256);   // 12 x 64 = 768

  for (int l = 0; l < NL; ++l) {
    ln_kernel<true><<<M, 256, 0, stream>>>(x, g1 + l * D, b1 + l * D, nx);
    wconv_kernel<<<gw, 256, 0, stream>>>(Wq + (size_t)l * D * D, wtA, D, D);
    wconv_kernel<<<gw, 256, 0, stream>>>(Wk + (size_t)l * D * D, wtA + 768 * 768, D, D);
    wconv_kernel<<<gw, 256, 0, stream>>>(Wv + (size_t)l * D * D, wtA + 2 * 768 * 768, D, D);
    gemm256_kernel<true, false, false, false><<<nwg_qkv, 512, 0, stream>>>(
        nx, wtA, nullptr, nullptr, qkvb, QKVW, D, D, SCALE_F, nbx_qkv);
    gemm64_kernel<<<gsim, 256, 0, stream>>>(
        nx, Wsim + (size_t)l * D * SIMC, s, SIMC, D);
    snorm_kernel<<<M, 64, 0, stream>>>(s, sbf);
    wconv_kernel<<<gw, 256, 0, stream>>>(Wo + (size_t)l * D * D, wtB, D, D);
    wconv_kernel<<<gw1, 256, 0, stream>>>(Wff1 + (size_t)l * D * FFD, wtC, FFD, D);
    wconv_kernel<<<gw2, 256, 0, stream>>>(Wff2 + (size_t)l * FFD * D, wtD, D, FFD);
    attn_kernel<<<B * NH, 256, 0, stream>>>(qkvb, sbf, ob);
    gemm256_kernel<false, true, false, true><<<nwg_o, 512, 0, stream>>>(
        ob, wtB, bo + l * D, x, x, D, D, 0, 1.0f, nbx_o);
    ln_kernel<true><<<M, 256, 0, stream>>>(x, g2 + l * D, b2 + l * D, nx);
    gemm256_kernel<true, true, true, false><<<nwg_f1, 512, 0, stream>>>(
        nx, wtC, bff1 + l * FFD, nullptr, hb, FFD, D, 0, 1.0f, nbx_f1);
    gemm256_kernel<false, true, false, true><<<nwg_o, 512, 0, stream>>>(
        hb, wtD, bff2 + l * D, x, x, D, FFD, 0, 1.0f, nbx_o);
  }
  ln_kernel<false><<<M, 256, 0, stream>>>(x, gf, bfin, d_out);
}

// Round 4
// 1662.527 us; speedup vs baseline: 5.1970x; 1.1259x over previous
//
#include <hip/hip_runtime.h>

typedef unsigned short u16;
typedef unsigned int u32;
typedef float f32x4 __attribute__((ext_vector_type(4)));
typedef __bf16 bf16x8 __attribute__((ext_vector_type(8)));

static constexpr int D = 768, FFD = 3072, SIMC = 192, NH = 8, HD = 96;
static constexpr int B = 128, K = 128, M = B * K, NL = 4;
static constexpr int QKVW = 2304;  // fused qkv width
static constexpr float SCALE_F = 0.10206207261596575f;  // 96^-0.5
static constexpr float SQRT_BOOST = 0.5477225575051661f; // sqrt(0.3)
static constexpr float EPS_F = 1e-5f;

__device__ __forceinline__ float bf2f(u16 u) {
  union { u32 i; float f; } v; v.i = ((u32)u) << 16; return v.f;
}
__device__ __forceinline__ u16 f2bf(float f) {
  union { float f; u32 i; } v; v.f = f;
  u32 u = v.i;
  u32 r = (u + 0x7FFFu + ((u >> 16) & 1u)) >> 16;
  return (u16)r;
}

// tanh-form GELU via v_exp_f32/v_rcp_f32; max |err| vs erf-GELU ~3e-3.
__device__ __forceinline__ float fast_gelu(float x) {
  float u2 = x * (2.3020585f + 0.102944f * x * x);  // 2*log2e*0.79788*(x+0.044715x^3)
  float e = __builtin_amdgcn_exp2f(u2);
  float r = __builtin_amdgcn_rcpf(1.0f + e);        // = 0.5*(1-tanh(u))
  return x - x * r;                                 // 0.5x(1+tanh(u))
}

__device__ __forceinline__ void gload16(const void* g, void* l) {
  __builtin_amdgcn_global_load_lds(
      (const __attribute__((address_space(1))) void*)g,
      (__attribute__((address_space(3))) void*)l, 16, 0, 0);
}

// ---------------- add positional embedding ----------------
__global__ __launch_bounds__(256) void addpos_kernel(
    const float* __restrict__ slots, const float* __restrict__ pos,
    float* __restrict__ x) {
  int i = blockIdx.x * 256 + threadIdx.x;
  int m = i / D;
  int d = i - m * D;
  x[i] = slots[i] + pos[(m & (K - 1)) * D + d];
}

// ---------------- layernorm ----------------
__device__ __forceinline__ float block_sum(float v, float* sbuf) {
#pragma unroll
  for (int off = 32; off > 0; off >>= 1) v += __shfl_xor(v, off, 64);
  int lane = threadIdx.x & 63, w = threadIdx.x >> 6;
  if (lane == 0) sbuf[w] = v;
  __syncthreads();
  v = sbuf[0] + sbuf[1] + sbuf[2] + sbuf[3];
  __syncthreads();
  return v;
}

template <bool OUT_BF16>
__global__ __launch_bounds__(256) void ln_kernel(
    const float* __restrict__ x, const float* __restrict__ g,
    const float* __restrict__ b, void* __restrict__ out) {
  __shared__ float sbuf[4];
  int row = blockIdx.x, tid = threadIdx.x;
  const float* xr = x + (size_t)row * D;
  float v0 = xr[tid], v1 = xr[tid + 256], v2 = xr[tid + 512];
  float s = block_sum(v0 + v1 + v2, sbuf);
  float mean = s * (1.0f / D);
  float d0 = v0 - mean, d1 = v1 - mean, d2 = v2 - mean;
  float sq = block_sum(d0 * d0 + d1 * d1 + d2 * d2, sbuf);
  float rs = rsqrtf(sq * (1.0f / D) + EPS_F);
  float y0 = d0 * rs * g[tid] + b[tid];
  float y1 = d1 * rs * g[tid + 256] + b[tid + 256];
  float y2 = d2 * rs * g[tid + 512] + b[tid + 512];
  if (OUT_BF16) {
    u16* o = (u16*)out + (size_t)row * D;
    o[tid] = f2bf(y0); o[tid + 256] = f2bf(y1); o[tid + 512] = f2bf(y2);
  } else {
    float* o = (float*)out + (size_t)row * D;
    o[tid] = y0; o[tid + 256] = y1; o[tid + 512] = y2;
  }
}

// ------------- merged QKVO weight transpose+convert (768x768 each) -------------
struct W4 {
  const float* w0; const float* w1; const float* w2; const float* w3;
  u16* o0; u16* o1; u16* o2; u16* o3;
};
__global__ __launch_bounds__(256) void wconv4_kernel(W4 p, float scale0) {
  __shared__ u16 t[32][33];
  int z = blockIdx.z;
  const float* W = z == 0 ? p.w0 : z == 1 ? p.w1 : z == 2 ? p.w2 : p.w3;
  u16* Wt = z == 0 ? p.o0 : z == 1 ? p.o1 : z == 2 ? p.o2 : p.o3;
  float sc = z == 0 ? scale0 : 1.0f;
  int n0 = blockIdx.x * 32, k0 = blockIdx.y * 32;
  int tid = threadIdx.x;
  int c = tid & 31, r4 = tid >> 5;
#pragma unroll
  for (int i = 0; i < 4; ++i) {
    int r = r4 + i * 8;
    t[r][c] = f2bf(W[(size_t)(k0 + r) * D + n0 + c] * sc);
  }
  __syncthreads();
#pragma unroll
  for (int i = 0; i < 4; ++i) {
    int r = r4 + i * 8;
    Wt[(size_t)(n0 + r) * D + k0 + c] = t[c][r];
  }
}

// ---------------- generic weight transpose+convert: W[Kd][N] f32 -> Wt[N][Kd] bf16 ----------------
__global__ __launch_bounds__(256) void wconv_kernel(
    const float* __restrict__ W, u16* __restrict__ Wt, int N, int Kd) {
  __shared__ u16 t[32][33];
  int n0 = blockIdx.x * 32, k0 = blockIdx.y * 32;
  int tid = threadIdx.x;
  int c = tid & 31, r4 = tid >> 5;
#pragma unroll
  for (int i = 0; i < 4; ++i) {
    int r = r4 + i * 8;
    t[r][c] = f2bf(W[(size_t)(k0 + r) * N + n0 + c]);
  }
  __syncthreads();
#pragma unroll
  for (int i = 0; i < 4; ++i) {
    int r = r4 + i * 8;
    Wt[(size_t)(n0 + r) * Kd + k0 + c] = t[c][r];
  }
}

// ===================== 256x256 8-phase GEMM (single-barrier phases) =====================
// C[M,N] = A[M,K](bf16) @ Bt[N,K]^T(bf16).  512 thr = 8 waves (2M x 4N), BK=64,
// LDS 128KB = 2 K-tile buffers x (A,B). XOR swizzle (rule 21): pre-swizzled global
// source + swizzled ds_read, linear gload_lds dest.
// Phase = { ds_reads, stage, lgkmcnt(0)[+vmcnt], s_barrier, MFMA }.
// Invariant: all waves' LDS reads of phase p complete before any wave passes p's
// barrier (lgkmcnt precedes barrier), so p+1 stage-writes cannot corrupt them.
// Stage/read ledger + vmcnt(4)@p4/p8 identical to the verified round-3 kernel:
// at p4: in-flight {t3'B(4), t1A(4), t2B(4)}, vmcnt(4) retires first 8 -> p5
// reads buf1.{A,B} landed; at p8: {t2B(4), t2A(4), t3B(4)}, vmcnt(4) retires
// 8 -> next p1 reads buf0.{A,B} landed. Last iter: p4 drains vmcnt(0), p5-p8
// stage nothing.
template <bool OUT_BF16, bool BIAS, bool GELU_, bool RESID>
__global__ __launch_bounds__(512, 2) void gemm256_kernel(
    const u16* __restrict__ A, const u16* __restrict__ Bt,
    const float* __restrict__ bias, const float* __restrict__ resid,
    void* __restrict__ Cout, int N, int Kdim, int NBX) {
  __shared__ u16 lds[65536];  // buf0.A | buf0.B | buf1.A | buf1.B (16384 u16 each)
  int tid = threadIdx.x;
  int w = tid >> 6, lane = tid & 63;
  int wm = w >> 2, wn = w & 3;
  int lr = lane & 15, lg = lane >> 4;

  // XCD-bijective swizzle (all grids divisible by 8)
  int nwg = gridDim.x;
  int cpx = nwg >> 3;
  int swz = (blockIdx.x & 7) * cpx + (blockIdx.x >> 3);
  int bx = swz % NBX, by = swz / NBX;
  int n0 = bx << 8, m0 = by << 8;

  int scol = ((lane & 7) ^ (lane >> 3)) << 3;  // pre-swizzled source col-block
  size_t aOff = (size_t)((w << 4) + (lane >> 3)) * Kdim + scol;
  u16* ldsU = lds;

  auto stageA = [&](int buf, int h, int t) {
    const u16* g = A + (size_t)(m0 + (h << 7)) * Kdim + ((size_t)t << 6) + aOff;
    u16* l = ldsU + buf * 32768 + h * 8192 + (w << 10);
    gload16(g, l);
    gload16(g + ((size_t)Kdim << 3), l + 512);
  };
  auto stageB = [&](int buf, int h, int t) {
    const u16* g = Bt + (size_t)(n0 + (h << 7)) * Kdim + ((size_t)t << 6) + aOff;
    u16* l = ldsU + buf * 32768 + 16384 + h * 8192 + (w << 10);
    gload16(g, l);
    gload16(g + ((size_t)Kdim << 3), l + 512);
  };

  const u16* lA0p = ldsU;
  const u16* lB0p = ldsU + 16384;
  const u16* lA1p = ldsU + 32768;
  const u16* lB1p = ldsU + 49152;
  int arow = (wm * 128 + lr) * 64;
  int brow = (wn * 64 + lr) * 64;
  int swz0 = (((lg * 16)) ^ ((lr & 7) << 4)) >> 1;
  int swz1 = ((64 + lg * 16) ^ ((lr & 7) << 4)) >> 1;

  f32x4 acc[8][4] = {};
  bf16x8 ar[2][4], br[2][4];

#define READ_A(BASE, MSEG)                                                   \
  do {                                                                       \
    _Pragma("unroll") for (int mm = 0; mm < 4; ++mm) {                       \
      const u16* p_ = (BASE) + arow + ((MSEG) * 64 + mm * 16) * 64;          \
      ar[0][mm] = *(const bf16x8*)(p_ + swz0);                               \
      ar[1][mm] = *(const bf16x8*)(p_ + swz1);                               \
    }                                                                        \
  } while (0)
#define READ_B(BASE, NSEG)                                                   \
  do {                                                                       \
    _Pragma("unroll") for (int nn = 0; nn < 2; ++nn) {                       \
      const u16* p_ = (BASE) + brow + ((NSEG) * 32 + nn * 16) * 64;          \
      br[0][(NSEG) * 2 + nn] = *(const bf16x8*)(p_ + swz0);                  \
      br[1][(NSEG) * 2 + nn] = *(const bf16x8*)(p_ + swz1);                  \
    }                                                                        \
  } while (0)
#define MFMA_Q(MSEG, NSEG)                                                   \
  do {                                                                       \
    __builtin_amdgcn_s_setprio(1);                                           \
    _Pragma("unroll") for (int ks = 0; ks < 2; ++ks)                         \
      _Pragma("unroll") for (int mm = 0; mm < 4; ++mm)                       \
        _Pragma("unroll") for (int nn = 0; nn < 2; ++nn)                     \
          acc[(MSEG) * 4 + mm][(NSEG) * 2 + nn] =                            \
              __builtin_amdgcn_mfma_f32_16x16x32_bf16(                       \
                  ar[ks][mm], br[ks][(NSEG) * 2 + nn],                       \
                  acc[(MSEG) * 4 + mm][(NSEG) * 2 + nn], 0, 0, 0);           \
    __builtin_amdgcn_s_setprio(0);                                           \
  } while (0)
// single-barrier phase sync: own LDS reads done -> [vmem fence] -> barrier
#define PSYNC()                                                              \
  do {                                                                       \
    __builtin_amdgcn_sched_barrier(0);                                       \
    asm volatile("s_waitcnt lgkmcnt(0)" ::: "memory");                       \
    __builtin_amdgcn_s_barrier();                                            \
    __builtin_amdgcn_sched_barrier(0);                                       \
  } while (0)
#define PSYNC_V(N)                                                           \
  do {                                                                       \
    __builtin_amdgcn_sched_barrier(0);                                       \
    asm volatile("s_waitcnt vmcnt(" #N ") lgkmcnt(0)" ::: "memory");         \
    __builtin_amdgcn_s_barrier();                                            \
    __builtin_amdgcn_sched_barrier(0);                                       \
  } while (0)

  int NK = Kdim >> 6, NI = NK >> 1;
  // ---- prologue: tile0 -> buf0 (4 halves), tile1 B -> buf1 ----
  stageA(0, 0, 0); stageA(0, 1, 0); stageB(0, 0, 0); stageB(0, 1, 0);
  stageB(1, 0, 1); stageB(1, 1, 1);
  asm volatile("s_waitcnt vmcnt(4)" ::: "memory");  // tile0 (oldest 8) landed
  __builtin_amdgcn_s_barrier();
  __builtin_amdgcn_sched_barrier(0);

  for (int i = 0; i < NI; ++i) {
    int t1 = 2 * i + 1, t2 = 2 * i + 2, t3 = 2 * i + 3;
    bool last = (i == NI - 1);
    // ---- p1 ----
    READ_A(lA0p, 0); READ_B(lB0p, 0);
    stageA(1, 0, t1);
    PSYNC(); MFMA_Q(0, 0);
    // ---- p2 ----
    READ_B(lB0p, 1);
    stageA(1, 1, t1);
    PSYNC(); MFMA_Q(0, 1);
    // ---- p3 ----
    READ_A(lA0p, 1);
    if (!last) stageB(0, 0, t2);
    PSYNC(); MFMA_Q(1, 0);
    // ---- p4 ----
    if (!last) { stageB(0, 1, t2); PSYNC_V(4); }
    else PSYNC_V(0);
    MFMA_Q(1, 1);
    // ---- p5 ----
    READ_A(lA1p, 0); READ_B(lB1p, 0);
    if (!last) stageA(0, 0, t2);
    PSYNC(); MFMA_Q(0, 0);
    // ---- p6 ----
    READ_B(lB1p, 1);
    if (!last) stageA(0, 1, t2);
    PSYNC(); MFMA_Q(0, 1);
    // ---- p7 ----
    READ_A(lA1p, 1);
    if (!last) stageB(1, 0, t3);
    PSYNC(); MFMA_Q(1, 0);
    // ---- p8 ----
    if (!last) { stageB(1, 1, t3); PSYNC_V(4); }
    else PSYNC();
    MFMA_Q(1, 1);
  }

  // ---- epilogue ----
#pragma unroll
  for (int m = 0; m < 8; ++m) {
#pragma unroll
    for (int n = 0; n < 4; ++n) {
      int col = n0 + wn * 64 + n * 16 + lr;
      float bv = BIAS ? bias[col] : 0.0f;
#pragma unroll
      for (int r = 0; r < 4; ++r) {
        int row = m0 + wm * 128 + m * 16 + lg * 4 + r;
        float v = acc[m][n][r];
        if (BIAS) v += bv;
        if (GELU_) v = fast_gelu(v);
        if (RESID) v += resid[(size_t)row * N + col];
        if (OUT_BF16) ((u16*)Cout)[(size_t)row * N + col] = f2bf(v);
        else ((float*)Cout)[(size_t)row * N + col] = v;
      }
    }
  }
#undef READ_A
#undef READ_B
#undef MFMA_Q
#undef PSYNC
#undef PSYNC_V
}

// ---------------- 64-tile GEMM (f32 B on the fly) for sim projection ----------------
__global__ __launch_bounds__(256) void gemm64_kernel(
    const u16* __restrict__ A, const float* __restrict__ Bw,
    float* __restrict__ Cout, int N, int Kdim) {
  __shared__ u16 lA[64][40];
  __shared__ u16 lB[64][40];
  int tid = threadIdx.x;
  int n0 = blockIdx.x * 64, m0 = blockIdx.y * 64;
  int w = tid >> 6, lane = tid & 63;
  int wr = w >> 1, wc = w & 1;
  int lr = lane & 15, lg = lane >> 4;
  f32x4 acc[2][2] = {};
  int ar = tid >> 2, ak = (tid & 3) * 8;
  int bk = tid >> 3, bn = (tid & 7) * 8;
  const u16* Ap = A + (size_t)(m0 + ar) * Kdim + ak;
  const float* Bp = Bw + (size_t)bk * N + n0 + bn;
  for (int kt = 0; kt < Kdim; kt += 32) {
    uint4 av = *(const uint4*)Ap;
    Ap += 32;
    float4 b0 = *(const float4*)Bp;
    float4 b1 = *(const float4*)(Bp + 4);
    Bp += (size_t)32 * N;
    *(uint4*)(&lA[ar][ak]) = av;
    u16 t[8] = {f2bf(b0.x), f2bf(b0.y), f2bf(b0.z), f2bf(b0.w),
                f2bf(b1.x), f2bf(b1.y), f2bf(b1.z), f2bf(b1.w)};
#pragma unroll
    for (int i = 0; i < 8; ++i) lB[bn + i][bk] = t[i];
    __syncthreads();
#pragma unroll
    for (int m = 0; m < 2; ++m) {
      bf16x8 af = *(const bf16x8*)(&lA[32 * wr + 16 * m + lr][8 * lg]);
#pragma unroll
      for (int n = 0; n < 2; ++n) {
        bf16x8 bf = *(const bf16x8*)(&lB[32 * wc + 16 * n + lr][8 * lg]);
        acc[m][n] = __builtin_amdgcn_mfma_f32_16x16x32_bf16(af, bf, acc[m][n], 0, 0, 0);
      }
    }
    __syncthreads();
  }
#pragma unroll
  for (int m = 0; m < 2; ++m)
#pragma unroll
    for (int n = 0; n < 2; ++n) {
      int col = n0 + 32 * wc + 16 * n + lr;
#pragma unroll
      for (int r = 0; r < 4; ++r) {
        int row = m0 + 32 * wr + 16 * m + 4 * lg + r;
        Cout[(size_t)row * N + col] = acc[m][n][r];
      }
    }
}

// ---------------- s-normalize: s_bf = sqrt(BOOST) * s / max(||s||, 1e-12) ----------------
__global__ __launch_bounds__(64) void snorm_kernel(
    const float* __restrict__ s, u16* __restrict__ sbf) {
  int row = blockIdx.x, lane = threadIdx.x;
  const float* sr = s + (size_t)row * SIMC;
  float v0 = sr[lane], v1 = sr[lane + 64], v2 = sr[lane + 128];
  float sq = v0 * v0 + v1 * v1 + v2 * v2;
#pragma unroll
  for (int off = 32; off > 0; off >>= 1) sq += __shfl_xor(sq, off, 64);
  float inv = SQRT_BOOST / fmaxf(sqrtf(sq), 1e-12f);
  u16* o = sbf + (size_t)row * SIMC;
  o[lane] = f2bf(v0 * inv);
  o[lane + 64] = f2bf(v1 * inv);
  o[lane + 128] = f2bf(v2 * inv);
}

// ---------------- MFMA attention: one block per (b,h), 4 waves x 32 q-rows ----------------
__global__ __launch_bounds__(256) void attn_kernel(
    const u16* __restrict__ qkv, const u16* __restrict__ sbf,
    u16* __restrict__ ob) {
  __shared__ u16 Vt[96][136];
  __shared__ u16 Pl[4][32][136];
  int bh = blockIdx.x, b = bh >> 3, h = bh & 7;
  int tid = threadIdx.x, w = tid >> 6, lane = tid & 63;
  int lr = lane & 15, lg = lane >> 4;
  const u16* qb = qkv + (size_t)b * K * QKVW + h * HD;
  const u16* kb = qb + D;
  const u16* vb = qb + 2 * D;
  const u16* sb = sbf + (size_t)b * K * SIMC;
  for (int idx = tid; idx < 128 * 12; idx += 256) {
    int r = idx / 12, db = idx - r * 12;
    uint4 v4 = *(const uint4*)(vb + (size_t)r * QKVW + db * 8);
    u32 vv[4] = {v4.x, v4.y, v4.z, v4.w};
#pragma unroll
    for (int j = 0; j < 4; ++j) {
      Vt[db * 8 + 2 * j][r] = (u16)(vv[j] & 0xffffu);
      Vt[db * 8 + 2 * j + 1][r] = (u16)(vv[j] >> 16);
    }
  }
  int q0 = 32 * w;
  f32x4 accs[2][8] = {};
#pragma unroll
  for (int ks = 0; ks < 3; ++ks) {
    bf16x8 af[2];
#pragma unroll
    for (int m = 0; m < 2; ++m)
      af[m] = *(const bf16x8*)(qb + (size_t)(q0 + 16 * m + lr) * QKVW + ks * 32 + lg * 8);
#pragma unroll
    for (int n = 0; n < 8; ++n) {
      bf16x8 bf = *(const bf16x8*)(kb + (size_t)(16 * n + lr) * QKVW + ks * 32 + lg * 8);
#pragma unroll
      for (int m = 0; m < 2; ++m)
        accs[m][n] = __builtin_amdgcn_mfma_f32_16x16x32_bf16(af[m], bf, accs[m][n], 0, 0, 0);
    }
  }
#pragma unroll
  for (int ks = 0; ks < 6; ++ks) {
    bf16x8 af[2];
#pragma unroll
    for (int m = 0; m < 2; ++m)
      af[m] = *(const bf16x8*)(sb + (size_t)(q0 + 16 * m + lr) * SIMC + ks * 32 + lg * 8);
#pragma unroll
    for (int n = 0; n < 8; ++n) {
      bf16x8 bf = *(const bf16x8*)(sb + (size_t)(16 * n + lr) * SIMC + ks * 32 + lg * 8);
#pragma unroll
      for (int m = 0; m < 2; ++m)
        accs[m][n] = __builtin_amdgcn_mfma_f32_16x16x32_bf16(af[m], bf, accs[m][n], 0, 0, 0);
    }
  }
#pragma unroll
  for (int m = 0; m < 2; ++m) {
    float mx[4] = {-3e38f, -3e38f, -3e38f, -3e38f};
#pragma unroll
    for (int n = 0; n < 8; ++n)
#pragma unroll
      for (int r = 0; r < 4; ++r) mx[r] = fmaxf(mx[r], accs[m][n][r]);
#pragma unroll
    for (int r = 0; r < 4; ++r) {
      mx[r] = fmaxf(mx[r], __shfl_xor(mx[r], 1, 64));
      mx[r] = fmaxf(mx[r], __shfl_xor(mx[r], 2, 64));
      mx[r] = fmaxf(mx[r], __shfl_xor(mx[r], 4, 64));
      mx[r] = fmaxf(mx[r], __shfl_xor(mx[r], 8, 64));
    }
    float sm[4] = {0.f, 0.f, 0.f, 0.f};
#pragma unroll
    for (int n = 0; n < 8; ++n)
#pragma unroll
      for (int r = 0; r < 4; ++r) {
        float e = expf(accs[m][n][r] - mx[r]);
        accs[m][n][r] = e;
        sm[r] += e;
      }
#pragma unroll
    for (int r = 0; r < 4; ++r) {
      sm[r] += __shfl_xor(sm[r], 1, 64);
      sm[r] += __shfl_xor(sm[r], 2, 64);
      sm[r] += __shfl_xor(sm[r], 4, 64);
      sm[r] += __shfl_xor(sm[r], 8, 64);
    }
    float inv[4];
#pragma unroll
    for (int r = 0; r < 4; ++r) inv[r] = 1.0f / sm[r];
#pragma unroll
    for (int n = 0; n < 8; ++n)
#pragma unroll
      for (int r = 0; r < 4; ++r)
        Pl[w][16 * m + 4 * lg + r][16 * n + lr] = f2bf(accs[m][n][r] * inv[r]);
  }
  __syncthreads();
  f32x4 acco[2][6] = {};
#pragma unroll
  for (int ks = 0; ks < 4; ++ks) {
    bf16x8 pa[2];
#pragma unroll
    for (int m = 0; m < 2; ++m)
      pa[m] = *(const bf16x8*)(&Pl[w][16 * m + lr][ks * 32 + lg * 8]);
#pragma unroll
    for (int n = 0; n < 6; ++n) {
      bf16x8 bv = *(const bf16x8*)(&Vt[16 * n + lr][ks * 32 + lg * 8]);
#pragma unroll
      for (int m = 0; m < 2; ++m)
        acco[m][n] = __builtin_amdgcn_mfma_f32_16x16x32_bf16(pa[m], bv, acco[m][n], 0, 0, 0);
    }
  }
  u16* obb = ob + (size_t)b * K * D + h * HD;
#pragma unroll
  for (int m = 0; m < 2; ++m)
#pragma unroll
    for (int n = 0; n < 6; ++n)
#pragma unroll
      for (int r = 0; r < 4; ++r)
        obb[(size_t)(q0 + 16 * m + 4 * lg + r) * D + 16 * n + lr] = f2bf(acco[m][n][r]);
}

// ---------------- host ----------------
extern "C" void kernel_launch(void* const* d_in, const int* in_sizes, int n_in,
                              void* d_out, int out_size, void* d_ws, size_t ws_size,
                              hipStream_t stream) {
  (void)in_sizes; (void)n_in; (void)out_size;
  const float* slots = (const float*)d_in[0];
  const float* pos   = (const float*)d_in[1];
  const float* Wq    = (const float*)d_in[2];
  const float* Wk    = (const float*)d_in[3];
  const float* Wv    = (const float*)d_in[4];
  const float* Wo    = (const float*)d_in[5];
  const float* bo    = (const float*)d_in[6];
  const float* Wsim  = (const float*)d_in[7];
  const float* g1    = (const float*)d_in[8];
  const float* b1    = (const float*)d_in[9];
  const float* g2    = (const float*)d_in[10];
  const float* b2    = (const float*)d_in[11];
  const float* Wff1  = (const float*)d_in[12];
  const float* bff1  = (const float*)d_in[13];
  const float* Wff2  = (const float*)d_in[14];
  const float* bff2  = (const float*)d_in[15];
  const float* gf    = (const float*)d_in[16];
  const float* bfin  = (const float*)d_in[17];

  char* p = (char*)d_ws;
  float* x    = (float*)p; p += (size_t)M * D * 4;        // 50.3 MB
  u16*   nx   = (u16*)p;   p += (size_t)M * D * 2;        // 25.2 MB
  u16*   qkvb = (u16*)p;   p += (size_t)M * QKVW * 2;     // 75.5 MB
  u16*   ob   = (u16*)p;   p += (size_t)M * D * 2;        // 25.2 MB
  float* s    = (float*)p; p += (size_t)M * SIMC * 4;     // 12.6 MB
  u16*   sbf  = (u16*)p;   p += (size_t)M * SIMC * 2;     // 6.3 MB
  u16*   wtA  = (u16*)p;   p += (size_t)QKVW * D * 2;     // 3.5 MB
  u16*   wtB  = (u16*)p;   p += (size_t)D * D * 2;        // 1.2 MB
  u16*   wtC  = (u16*)p;   p += (size_t)FFD * D * 2;      // 4.7 MB
  u16*   wtD  = (u16*)p;   p += (size_t)D * FFD * 2;      // 4.7 MB
  if ((size_t)(p - (char*)d_ws) > ws_size) return;
  u16* hb = qkvb;  // [M][3072] ffn hidden (spans qkvb+ob, both dead during FFN)

  addpos_kernel<<<M * D / 256, 256, 0, stream>>>(slots, pos, x);

  dim3 gw4(24, 24, 4);
  dim3 gw1(96, 24);
  dim3 gw2(24, 96);
  dim3 gsim(SIMC / 64, M / 64);
  int nbx_qkv = QKVW / 256, nwg_qkv = nbx_qkv * (M / 256);  // 9 x 64 = 576
  int nbx_o   = D / 256,    nwg_o   = nbx_o * (M / 256);    // 3 x 64 = 192
  int nbx_f1  = FFD / 256,  nwg_f1  = nbx_f1 * (M / 256);   // 12 x 64 = 768

  for (int l = 0; l < NL; ++l) {
    ln_kernel<true><<<M, 256, 0, stream>>>(x, g1 + l * D, b1 + l * D, nx);
    W4 wp = {Wq + (size_t)l * D * D, Wk + (size_t)l * D * D,
             Wv + (size_t)l * D * D, Wo + (size_t)l * D * D,
             wtA, wtA + D * D, wtA + 2 * D * D, wtB};
    wconv4_kernel<<<gw4, 256, 0, stream>>>(wp, SCALE_F);
    wconv_kernel<<<gw1, 256, 0, stream>>>(Wff1 + (size_t)l * D * FFD, wtC, FFD, D);
    wconv_kernel<<<gw2, 256, 0, stream>>>(Wff2 + (size_t)l * FFD * D, wtD, D, FFD);
    gemm256_kernel<true, false, false, false><<<nwg_qkv, 512, 0, stream>>>(
        nx, wtA, nullptr, nullptr, qkvb, QKVW, D, nbx_qkv);
    gemm64_kernel<<<gsim, 256, 0, stream>>>(
        nx, Wsim + (size_t)l * D * SIMC, s, SIMC, D);
    snorm_kernel<<<M, 64, 0, stream>>>(s, sbf);
    attn_kernel<<<B * NH, 256, 0, stream>>>(qkvb, sbf, ob);
    gemm256_kernel<false, true, false, true><<<nwg_o, 512, 0, stream>>>(
        ob, wtB, bo + l * D, x, x, D, D, nbx_o);
    ln_kernel<true><<<M, 256, 0, stream>>>(x, g2 + l * D, b2 + l * D, nx);
    gemm256_kernel<true, true, true, false><<<nwg_f1, 512, 0, stream>>>(
        nx, wtC, bff1 + l * FFD, nullptr, hb, FFD, D, nbx_f1);
    gemm256_kernel<false, true, false, true><<<nwg_o, 512, 0, stream>>>(
        hb, wtD, bff2 + l * D, x, x, D, FFD, nbx_o);
  }
  ln_kernel<false><<<M, 256, 0, stream>>>(x, gf, bfin, d_out);
}

// Round 5
// 1524.294 us; speedup vs baseline: 5.6683x; 1.0907x over previous
//
#include <hip/hip_runtime.h>

typedef unsigned short u16;
typedef unsigned int u32;
typedef float f32x4 __attribute__((ext_vector_type(4)));
typedef __bf16 bf16x8 __attribute__((ext_vector_type(8)));

static constexpr int D = 768, FFD = 3072, SIMC = 192, NH = 8, HD = 96;
static constexpr int B = 128, K = 128, M = B * K, NL = 4;
static constexpr int QKVW = 2560;   // q(768) k(768) v(768) s(192) pad(64)
static constexpr int SIMOFF = 2304;
// Q pre-scale = HD^-0.5 * log2(e)  (softmax runs in exp2 domain)
static constexpr float QSCALE = 0.14724502f;
// s pre-scale = sqrt(BOOST * log2(e))
static constexpr float SBOOST2 = 0.6578821f;
static constexpr float EPS_F = 1e-5f;

__device__ __forceinline__ float bf2f(u16 u) {
  union { u32 i; float f; } v; v.i = ((u32)u) << 16; return v.f;
}
__device__ __forceinline__ u16 f2bf(float f) {
  union { float f; u32 i; } v; v.f = f;
  u32 u = v.i;
  u32 r = (u + 0x7FFFu + ((u >> 16) & 1u)) >> 16;
  return (u16)r;
}

// tanh-form GELU via v_exp_f32/v_rcp_f32; max |err| vs erf-GELU ~3e-3.
__device__ __forceinline__ float fast_gelu(float x) {
  float u2 = x * (2.3020585f + 0.102944f * x * x);
  float e = __builtin_amdgcn_exp2f(u2);
  float r = __builtin_amdgcn_rcpf(1.0f + e);
  return x - x * r;
}

__device__ __forceinline__ void gload16(const void* g, void* l) {
  __builtin_amdgcn_global_load_lds(
      (const __attribute__((address_space(1))) void*)g,
      (__attribute__((address_space(3))) void*)l, 16, 0, 0);
}

// ---------------- add positional embedding (x is bf16 residual stream) ----------------
__global__ __launch_bounds__(256) void addpos_kernel(
    const float* __restrict__ slots, const float* __restrict__ pos,
    u16* __restrict__ x) {
  int i = blockIdx.x * 256 + threadIdx.x;
  int m = i / D;
  int d = i - m * D;
  x[i] = f2bf(slots[i] + pos[(m & (K - 1)) * D + d]);
}

// ---------------- layernorm (bf16 in; bf16 or f32 out) ----------------
__device__ __forceinline__ float block_sum(float v, float* sbuf) {
#pragma unroll
  for (int off = 32; off > 0; off >>= 1) v += __shfl_xor(v, off, 64);
  int lane = threadIdx.x & 63, w = threadIdx.x >> 6;
  if (lane == 0) sbuf[w] = v;
  __syncthreads();
  v = sbuf[0] + sbuf[1] + sbuf[2] + sbuf[3];
  __syncthreads();
  return v;
}

template <bool OUT_BF16>
__global__ __launch_bounds__(256) void ln_kernel(
    const u16* __restrict__ x, const float* __restrict__ g,
    const float* __restrict__ b, void* __restrict__ out) {
  __shared__ float sbuf[4];
  int row = blockIdx.x, tid = threadIdx.x;
  const u16* xr = x + (size_t)row * D;
  float v0 = bf2f(xr[tid]), v1 = bf2f(xr[tid + 256]), v2 = bf2f(xr[tid + 512]);
  float s = block_sum(v0 + v1 + v2, sbuf);
  float mean = s * (1.0f / D);
  float d0 = v0 - mean, d1 = v1 - mean, d2 = v2 - mean;
  float sq = block_sum(d0 * d0 + d1 * d1 + d2 * d2, sbuf);
  float rs = rsqrtf(sq * (1.0f / D) + EPS_F);
  float y0 = d0 * rs * g[tid] + b[tid];
  float y1 = d1 * rs * g[tid + 256] + b[tid + 256];
  float y2 = d2 * rs * g[tid + 512] + b[tid + 512];
  if (OUT_BF16) {
    u16* o = (u16*)out + (size_t)row * D;
    o[tid] = f2bf(y0); o[tid + 256] = f2bf(y1); o[tid + 512] = f2bf(y2);
  } else {
    float* o = (float*)out + (size_t)row * D;
    o[tid] = y0; o[tid + 256] = y1; o[tid + 512] = y2;
  }
}

// ------------- merged QKVO weight transpose+convert (768x768 each) -------------
struct W4 {
  const float* w0; const float* w1; const float* w2; const float* w3;
  u16* o0; u16* o1; u16* o2; u16* o3;
};
__global__ __launch_bounds__(256) void wconv4_kernel(W4 p, float scale0) {
  __shared__ u16 t[32][33];
  int z = blockIdx.z;
  const float* W = z == 0 ? p.w0 : z == 1 ? p.w1 : z == 2 ? p.w2 : p.w3;
  u16* Wt = z == 0 ? p.o0 : z == 1 ? p.o1 : z == 2 ? p.o2 : p.o3;
  float sc = z == 0 ? scale0 : 1.0f;
  int n0 = blockIdx.x * 32, k0 = blockIdx.y * 32;
  int tid = threadIdx.x;
  int c = tid & 31, r4 = tid >> 5;
#pragma unroll
  for (int i = 0; i < 4; ++i) {
    int r = r4 + i * 8;
    t[r][c] = f2bf(W[(size_t)(k0 + r) * D + n0 + c] * sc);
  }
  __syncthreads();
#pragma unroll
  for (int i = 0; i < 4; ++i) {
    int r = r4 + i * 8;
    Wt[(size_t)(n0 + r) * D + k0 + c] = t[c][r];
  }
}

// ---------------- generic weight transpose+convert: W[Kd][N] f32 -> Wt[N][Kd] bf16 ----------------
__global__ __launch_bounds__(256) void wconv_kernel(
    const float* __restrict__ W, u16* __restrict__ Wt, int N, int Kd) {
  __shared__ u16 t[32][33];
  int n0 = blockIdx.x * 32, k0 = blockIdx.y * 32;
  int tid = threadIdx.x;
  int c = tid & 31, r4 = tid >> 5;
#pragma unroll
  for (int i = 0; i < 4; ++i) {
    int r = r4 + i * 8;
    t[r][c] = f2bf(W[(size_t)(k0 + r) * N + n0 + c]);
  }
  __syncthreads();
#pragma unroll
  for (int i = 0; i < 4; ++i) {
    int r = r4 + i * 8;
    Wt[(size_t)(n0 + r) * Kd + k0 + c] = t[c][r];
  }
}

// ===================== 256x256 8-phase GEMM (single-barrier phases) =====================
// Identical schedule/ledger to the verified round-4 kernel; only the resid
// input is now bf16. See round-4 comments for the stage/read ledger.
template <bool OUT_BF16, bool BIAS, bool GELU_, bool RESID>
__global__ __launch_bounds__(512, 2) void gemm256_kernel(
    const u16* __restrict__ A, const u16* __restrict__ Bt,
    const float* __restrict__ bias, const u16* __restrict__ resid,
    void* __restrict__ Cout, int N, int Kdim, int NBX) {
  __shared__ u16 lds[65536];
  int tid = threadIdx.x;
  int w = tid >> 6, lane = tid & 63;
  int wm = w >> 2, wn = w & 3;
  int lr = lane & 15, lg = lane >> 4;

  int nwg = gridDim.x;
  int cpx = nwg >> 3;
  int swz = (blockIdx.x & 7) * cpx + (blockIdx.x >> 3);
  int bx = swz % NBX, by = swz / NBX;
  int n0 = bx << 8, m0 = by << 8;

  int scol = ((lane & 7) ^ (lane >> 3)) << 3;
  size_t aOff = (size_t)((w << 4) + (lane >> 3)) * Kdim + scol;
  u16* ldsU = lds;

  auto stageA = [&](int buf, int h, int t) {
    const u16* g = A + (size_t)(m0 + (h << 7)) * Kdim + ((size_t)t << 6) + aOff;
    u16* l = ldsU + buf * 32768 + h * 8192 + (w << 10);
    gload16(g, l);
    gload16(g + ((size_t)Kdim << 3), l + 512);
  };
  auto stageB = [&](int buf, int h, int t) {
    const u16* g = Bt + (size_t)(n0 + (h << 7)) * Kdim + ((size_t)t << 6) + aOff;
    u16* l = ldsU + buf * 32768 + 16384 + h * 8192 + (w << 10);
    gload16(g, l);
    gload16(g + ((size_t)Kdim << 3), l + 512);
  };

  const u16* lA0p = ldsU;
  const u16* lB0p = ldsU + 16384;
  const u16* lA1p = ldsU + 32768;
  const u16* lB1p = ldsU + 49152;
  int arow = (wm * 128 + lr) * 64;
  int brow = (wn * 64 + lr) * 64;
  int swz0 = (((lg * 16)) ^ ((lr & 7) << 4)) >> 1;
  int swz1 = ((64 + lg * 16) ^ ((lr & 7) << 4)) >> 1;

  f32x4 acc[8][4] = {};
  bf16x8 ar[2][4], br[2][4];

#define READ_A(BASE, MSEG)                                                   \
  do {                                                                       \
    _Pragma("unroll") for (int mm = 0; mm < 4; ++mm) {                       \
      const u16* p_ = (BASE) + arow + ((MSEG) * 64 + mm * 16) * 64;          \
      ar[0][mm] = *(const bf16x8*)(p_ + swz0);                               \
      ar[1][mm] = *(const bf16x8*)(p_ + swz1);                               \
    }                                                                        \
  } while (0)
#define READ_B(BASE, NSEG)                                                   \
  do {                                                                       \
    _Pragma("unroll") for (int nn = 0; nn < 2; ++nn) {                       \
      const u16* p_ = (BASE) + brow + ((NSEG) * 32 + nn * 16) * 64;          \
      br[0][(NSEG) * 2 + nn] = *(const bf16x8*)(p_ + swz0);                  \
      br[1][(NSEG) * 2 + nn] = *(const bf16x8*)(p_ + swz1);                  \
    }                                                                        \
  } while (0)
#define MFMA_Q(MSEG, NSEG)                                                   \
  do {                                                                       \
    __builtin_amdgcn_s_setprio(1);                                           \
    _Pragma("unroll") for (int ks = 0; ks < 2; ++ks)                         \
      _Pragma("unroll") for (int mm = 0; mm < 4; ++mm)                       \
        _Pragma("unroll") for (int nn = 0; nn < 2; ++nn)                     \
          acc[(MSEG) * 4 + mm][(NSEG) * 2 + nn] =                            \
              __builtin_amdgcn_mfma_f32_16x16x32_bf16(                       \
                  ar[ks][mm], br[ks][(NSEG) * 2 + nn],                       \
                  acc[(MSEG) * 4 + mm][(NSEG) * 2 + nn], 0, 0, 0);           \
    __builtin_amdgcn_s_setprio(0);                                           \
  } while (0)
#define PSYNC()                                                              \
  do {                                                                       \
    __builtin_amdgcn_sched_barrier(0);                                       \
    asm volatile("s_waitcnt lgkmcnt(0)" ::: "memory");                       \
    __builtin_amdgcn_s_barrier();                                            \
    __builtin_amdgcn_sched_barrier(0);                                       \
  } while (0)
#define PSYNC_V(N)                                                           \
  do {                                                                       \
    __builtin_amdgcn_sched_barrier(0);                                       \
    asm volatile("s_waitcnt vmcnt(" #N ") lgkmcnt(0)" ::: "memory");         \
    __builtin_amdgcn_s_barrier();                                            \
    __builtin_amdgcn_sched_barrier(0);                                       \
  } while (0)

  int NK = Kdim >> 6, NI = NK >> 1;
  stageA(0, 0, 0); stageA(0, 1, 0); stageB(0, 0, 0); stageB(0, 1, 0);
  stageB(1, 0, 1); stageB(1, 1, 1);
  asm volatile("s_waitcnt vmcnt(4)" ::: "memory");
  __builtin_amdgcn_s_barrier();
  __builtin_amdgcn_sched_barrier(0);

  for (int i = 0; i < NI; ++i) {
    int t1 = 2 * i + 1, t2 = 2 * i + 2, t3 = 2 * i + 3;
    bool last = (i == NI - 1);
    READ_A(lA0p, 0); READ_B(lB0p, 0);
    stageA(1, 0, t1);
    PSYNC(); MFMA_Q(0, 0);
    READ_B(lB0p, 1);
    stageA(1, 1, t1);
    PSYNC(); MFMA_Q(0, 1);
    READ_A(lA0p, 1);
    if (!last) stageB(0, 0, t2);
    PSYNC(); MFMA_Q(1, 0);
    if (!last) { stageB(0, 1, t2); PSYNC_V(4); }
    else PSYNC_V(0);
    MFMA_Q(1, 1);
    READ_A(lA1p, 0); READ_B(lB1p, 0);
    if (!last) stageA(0, 0, t2);
    PSYNC(); MFMA_Q(0, 0);
    READ_B(lB1p, 1);
    if (!last) stageA(0, 1, t2);
    PSYNC(); MFMA_Q(0, 1);
    READ_A(lA1p, 1);
    if (!last) stageB(1, 0, t3);
    PSYNC(); MFMA_Q(1, 0);
    if (!last) { stageB(1, 1, t3); PSYNC_V(4); }
    else PSYNC();
    MFMA_Q(1, 1);
  }

#pragma unroll
  for (int m = 0; m < 8; ++m) {
#pragma unroll
    for (int n = 0; n < 4; ++n) {
      int col = n0 + wn * 64 + n * 16 + lr;
      float bv = BIAS ? bias[col] : 0.0f;
#pragma unroll
      for (int r = 0; r < 4; ++r) {
        int row = m0 + wm * 128 + m * 16 + lg * 4 + r;
        float v = acc[m][n][r];
        if (BIAS) v += bv;
        if (GELU_) v = fast_gelu(v);
        if (RESID) v += bf2f(resid[(size_t)row * N + col]);
        if (OUT_BF16) ((u16*)Cout)[(size_t)row * N + col] = f2bf(v);
        else ((float*)Cout)[(size_t)row * N + col] = v;
      }
    }
  }
#undef READ_A
#undef READ_B
#undef MFMA_Q
#undef PSYNC
#undef PSYNC_V
}

// --------- s-normalize: sbf = sqrt(BOOST*log2e) * s / max(||s||,1e-12) ---------
// s read as bf16 from the fused qkv output (cols SIMOFF..SIMOFF+192).
__global__ __launch_bounds__(64) void snorm_kernel(
    const u16* __restrict__ qkvb, u16* __restrict__ sbf) {
  int row = blockIdx.x, lane = threadIdx.x;
  const u16* sr = qkvb + (size_t)row * QKVW + SIMOFF;
  float v0 = bf2f(sr[lane]), v1 = bf2f(sr[lane + 64]), v2 = bf2f(sr[lane + 128]);
  float sq = v0 * v0 + v1 * v1 + v2 * v2;
#pragma unroll
  for (int off = 32; off > 0; off >>= 1) sq += __shfl_xor(sq, off, 64);
  float inv = SBOOST2 / fmaxf(sqrtf(sq), 1e-12f);
  u16* o = sbf + (size_t)row * SIMC;
  o[lane] = f2bf(v0 * inv);
  o[lane + 64] = f2bf(v1 * inv);
  o[lane + 128] = f2bf(v2 * inv);
}

// ---------------- MFMA attention: one block per (b,h), 4 waves x 32 q-rows ----------------
// scores(log2-domain) = (QSCALE*Q)K^T + sbf sbf^T ; softmax via exp2.
__global__ __launch_bounds__(256) void attn_kernel(
    const u16* __restrict__ qkv, const u16* __restrict__ sbf,
    u16* __restrict__ ob) {
  __shared__ u16 Vt[96][136];
  __shared__ u16 Pl[4][32][136];
  int bh = blockIdx.x, b = bh >> 3, h = bh & 7;
  int tid = threadIdx.x, w = tid >> 6, lane = tid & 63;
  int lr = lane & 15, lg = lane >> 4;
  const u16* qb = qkv + (size_t)b * K * QKVW + h * HD;
  const u16* kb = qb + D;
  const u16* vb = qb + 2 * D;
  const u16* sb = sbf + (size_t)b * K * SIMC;
  for (int idx = tid; idx < 128 * 12; idx += 256) {
    int r = idx / 12, db = idx - r * 12;
    uint4 v4 = *(const uint4*)(vb + (size_t)r * QKVW + db * 8);
    u32 vv[4] = {v4.x, v4.y, v4.z, v4.w};
#pragma unroll
    for (int j = 0; j < 4; ++j) {
      Vt[db * 8 + 2 * j][r] = (u16)(vv[j] & 0xffffu);
      Vt[db * 8 + 2 * j + 1][r] = (u16)(vv[j] >> 16);
    }
  }
  int q0 = 32 * w;
  f32x4 accs[2][8] = {};
#pragma unroll
  for (int ks = 0; ks < 3; ++ks) {
    bf16x8 af[2];
#pragma unroll
    for (int m = 0; m < 2; ++m)
      af[m] = *(const bf16x8*)(qb + (size_t)(q0 + 16 * m + lr) * QKVW + ks * 32 + lg * 8);
#pragma unroll
    for (int n = 0; n < 8; ++n) {
      bf16x8 bf = *(const bf16x8*)(kb + (size_t)(16 * n + lr) * QKVW + ks * 32 + lg * 8);
#pragma unroll
      for (int m = 0; m < 2; ++m)
        accs[m][n] = __builtin_amdgcn_mfma_f32_16x16x32_bf16(af[m], bf, accs[m][n], 0, 0, 0);
    }
  }
#pragma unroll
  for (int ks = 0; ks < 6; ++ks) {
    bf16x8 af[2];
#pragma unroll
    for (int m = 0; m < 2; ++m)
      af[m] = *(const bf16x8*)(sb + (size_t)(q0 + 16 * m + lr) * SIMC + ks * 32 + lg * 8);
#pragma unroll
    for (int n = 0; n < 8; ++n) {
      bf16x8 bf = *(const bf16x8*)(sb + (size_t)(16 * n + lr) * SIMC + ks * 32 + lg * 8);
#pragma unroll
      for (int m = 0; m < 2; ++m)
        accs[m][n] = __builtin_amdgcn_mfma_f32_16x16x32_bf16(af[m], bf, accs[m][n], 0, 0, 0);
    }
  }
#pragma unroll
  for (int m = 0; m < 2; ++m) {
    float mx[4] = {-3e38f, -3e38f, -3e38f, -3e38f};
#pragma unroll
    for (int n = 0; n < 8; ++n)
#pragma unroll
      for (int r = 0; r < 4; ++r) mx[r] = fmaxf(mx[r], accs[m][n][r]);
#pragma unroll
    for (int r = 0; r < 4; ++r) {
      mx[r] = fmaxf(mx[r], __shfl_xor(mx[r], 1, 64));
      mx[r] = fmaxf(mx[r], __shfl_xor(mx[r], 2, 64));
      mx[r] = fmaxf(mx[r], __shfl_xor(mx[r], 4, 64));
      mx[r] = fmaxf(mx[r], __shfl_xor(mx[r], 8, 64));
    }
    float sm[4] = {0.f, 0.f, 0.f, 0.f};
#pragma unroll
    for (int n = 0; n < 8; ++n)
#pragma unroll
      for (int r = 0; r < 4; ++r) {
        float e = __builtin_amdgcn_exp2f(accs[m][n][r] - mx[r]);
        accs[m][n][r] = e;
        sm[r] += e;
      }
#pragma unroll
    for (int r = 0; r < 4; ++r) {
      sm[r] += __shfl_xor(sm[r], 1, 64);
      sm[r] += __shfl_xor(sm[r], 2, 64);
      sm[r] += __shfl_xor(sm[r], 4, 64);
      sm[r] += __shfl_xor(sm[r], 8, 64);
    }
    float inv[4];
#pragma unroll
    for (int r = 0; r < 4; ++r) inv[r] = 1.0f / sm[r];
#pragma unroll
    for (int n = 0; n < 8; ++n)
#pragma unroll
      for (int r = 0; r < 4; ++r)
        Pl[w][16 * m + 4 * lg + r][16 * n + lr] = f2bf(accs[m][n][r] * inv[r]);
  }
  __syncthreads();
  f32x4 acco[2][6] = {};
#pragma unroll
  for (int ks = 0; ks < 4; ++ks) {
    bf16x8 pa[2];
#pragma unroll
    for (int m = 0; m < 2; ++m)
      pa[m] = *(const bf16x8*)(&Pl[w][16 * m + lr][ks * 32 + lg * 8]);
#pragma unroll
    for (int n = 0; n < 6; ++n) {
      bf16x8 bv = *(const bf16x8*)(&Vt[16 * n + lr][ks * 32 + lg * 8]);
#pragma unroll
      for (int m = 0; m < 2; ++m)
        acco[m][n] = __builtin_amdgcn_mfma_f32_16x16x32_bf16(pa[m], bv, acco[m][n], 0, 0, 0);
    }
  }
  u16* obb = ob + (size_t)b * K * D + h * HD;
#pragma unroll
  for (int m = 0; m < 2; ++m)
#pragma unroll
    for (int n = 0; n < 6; ++n)
#pragma unroll
      for (int r = 0; r < 4; ++r)
        obb[(size_t)(q0 + 16 * m + 4 * lg + r) * D + 16 * n + lr] = f2bf(acco[m][n][r]);
}

// ---------------- host ----------------
extern "C" void kernel_launch(void* const* d_in, const int* in_sizes, int n_in,
                              void* d_out, int out_size, void* d_ws, size_t ws_size,
                              hipStream_t stream) {
  (void)in_sizes; (void)n_in; (void)out_size;
  const float* slots = (const float*)d_in[0];
  const float* pos   = (const float*)d_in[1];
  const float* Wq    = (const float*)d_in[2];
  const float* Wk    = (const float*)d_in[3];
  const float* Wv    = (const float*)d_in[4];
  const float* Wo    = (const float*)d_in[5];
  const float* bo    = (const float*)d_in[6];
  const float* Wsim  = (const float*)d_in[7];
  const float* g1    = (const float*)d_in[8];
  const float* b1    = (const float*)d_in[9];
  const float* g2    = (const float*)d_in[10];
  const float* b2    = (const float*)d_in[11];
  const float* Wff1  = (const float*)d_in[12];
  const float* bff1  = (const float*)d_in[13];
  const float* Wff2  = (const float*)d_in[14];
  const float* bff2  = (const float*)d_in[15];
  const float* gf    = (const float*)d_in[16];
  const float* bfin  = (const float*)d_in[17];

  char* p = (char*)d_ws;
  u16*   x    = (u16*)p;   p += (size_t)M * D * 2;        // 25.2 MB (bf16 residual)
  u16*   nx   = (u16*)p;   p += (size_t)M * D * 2;        // 25.2 MB
  u16*   qkvb = (u16*)p;   p += (size_t)M * QKVW * 2;     // 83.9 MB
  u16*   ob   = (u16*)p;   p += (size_t)M * D * 2;        // 25.2 MB
  u16*   sbf  = (u16*)p;   p += (size_t)M * SIMC * 2;     // 6.3 MB
  u16*   wtA  = (u16*)p;   p += (size_t)QKVW * D * 2;     // 3.9 MB (qkv + sim + pad)
  u16*   wtB  = (u16*)p;   p += (size_t)D * D * 2;        // 1.2 MB
  u16*   wtC  = (u16*)p;   p += (size_t)FFD * D * 2;      // 4.7 MB
  u16*   wtD  = (u16*)p;   p += (size_t)D * FFD * 2;      // 4.7 MB
  if ((size_t)(p - (char*)d_ws) > ws_size) return;
  u16* hb = qkvb;  // [M][3072] ffn hidden (spans qkvb+ob = 109 MB >= 100.7 MB)

  // zero the 64 pad rows of wtA once per call (never overwritten by wconvs)
  hipMemsetAsync(wtA + (size_t)(SIMOFF + SIMC) * D, 0, (size_t)64 * D * 2, stream);

  addpos_kernel<<<M * D / 256, 256, 0, stream>>>(slots, pos, x);

  dim3 gw4(24, 24, 4);
  dim3 gwsim(SIMC / 32, 24);
  dim3 gw1(96, 24);
  dim3 gw2(24, 96);
  int nbx_qkv = QKVW / 256, nwg_qkv = nbx_qkv * (M / 256);  // 10 x 64 = 640
  int nbx_o   = D / 256,    nwg_o   = nbx_o * (M / 256);    // 3 x 64 = 192
  int nbx_f1  = FFD / 256,  nwg_f1  = nbx_f1 * (M / 256);   // 12 x 64 = 768

  for (int l = 0; l < NL; ++l) {
    ln_kernel<true><<<M, 256, 0, stream>>>(x, g1 + l * D, b1 + l * D, nx);
    W4 wp = {Wq + (size_t)l * D * D, Wk + (size_t)l * D * D,
             Wv + (size_t)l * D * D, Wo + (size_t)l * D * D,
             wtA, wtA + D * D, wtA + 2 * D * D, wtB};
    wconv4_kernel<<<gw4, 256, 0, stream>>>(wp, QSCALE);
    wconv_kernel<<<gwsim, 256, 0, stream>>>(Wsim + (size_t)l * D * SIMC,
                                            wtA + (size_t)SIMOFF * D, SIMC, D);
    wconv_kernel<<<gw1, 256, 0, stream>>>(Wff1 + (size_t)l * D * FFD, wtC, FFD, D);
    wconv_kernel<<<gw2, 256, 0, stream>>>(Wff2 + (size_t)l * FFD * D, wtD, D, FFD);
    gemm256_kernel<true, false, false, false><<<nwg_qkv, 512, 0, stream>>>(
        nx, wtA, nullptr, nullptr, qkvb, QKVW, D, nbx_qkv);
    snorm_kernel<<<M, 64, 0, stream>>>(qkvb, sbf);
    attn_kernel<<<B * NH, 256, 0, stream>>>(qkvb, sbf, ob);
    gemm256_kernel<true, true, false, true><<<nwg_o, 512, 0, stream>>>(
        ob, wtB, bo + l * D, x, x, D, D, nbx_o);
    ln_kernel<true><<<M, 256, 0, stream>>>(x, g2 + l * D, b2 + l * D, nx);
    gemm256_kernel<true, true, true, false><<<nwg_f1, 512, 0, stream>>>(
        nx, wtC, bff1 + l * FFD, nullptr, hb, FFD, D, nbx_f1);
    gemm256_kernel<true, true, false, true><<<nwg_o, 512, 0, stream>>>(
        hb, wtD, bff2 + l * D, x, x, D, FFD, nbx_o);
  }
  ln_kernel<false><<<M, 256, 0, stream>>>(x, gf, bfin, d_out);
}

// Round 6
// 1508.057 us; speedup vs baseline: 5.7294x; 1.0108x over previous
//
#include <hip/hip_runtime.h>

typedef unsigned short u16;
typedef unsigned int u32;
typedef float f32x4 __attribute__((ext_vector_type(4)));
typedef __bf16 bf16x8 __attribute__((ext_vector_type(8)));

static constexpr int D = 768, FFD = 3072, SIMC = 192, NH = 8, HD = 96;
static constexpr int B = 128, K = 128, M = B * K, NL = 4;
static constexpr int QKVW = 2560;   // q(768) k(768) v(768) s(192) pad(64)
static constexpr int SIMOFF = 2304;
// Q pre-scale = HD^-0.5 * log2(e)  (softmax runs in exp2 domain)
static constexpr float QSCALE = 0.14724502f;
// s pre-scale = sqrt(BOOST * log2(e))
static constexpr float SBOOST2 = 0.6578821f;
static constexpr float EPS_F = 1e-5f;

__device__ __forceinline__ float bf2f(u16 u) {
  union { u32 i; float f; } v; v.i = ((u32)u) << 16; return v.f;
}
__device__ __forceinline__ u16 f2bf(float f) {
  union { float f; u32 i; } v; v.f = f;
  u32 u = v.i;
  u32 r = (u + 0x7FFFu + ((u >> 16) & 1u)) >> 16;
  return (u16)r;
}

// tanh-form GELU via v_exp_f32/v_rcp_f32; max |err| vs erf-GELU ~3e-3.
__device__ __forceinline__ float fast_gelu(float x) {
  float u2 = x * (2.3020585f + 0.102944f * x * x);
  float e = __builtin_amdgcn_exp2f(u2);
  float r = __builtin_amdgcn_rcpf(1.0f + e);
  return x - x * r;
}

__device__ __forceinline__ void gload16(const void* g, void* l) {
  __builtin_amdgcn_global_load_lds(
      (const __attribute__((address_space(1))) void*)g,
      (__attribute__((address_space(3))) void*)l, 16, 0, 0);
}

// ---------------- add positional embedding (x is bf16 residual stream) ----------------
__global__ __launch_bounds__(256) void addpos_kernel(
    const float* __restrict__ slots, const float* __restrict__ pos,
    u16* __restrict__ x) {
  int i = blockIdx.x * 256 + threadIdx.x;
  int m = i / D;
  int d = i - m * D;
  x[i] = f2bf(slots[i] + pos[(m & (K - 1)) * D + d]);
}

// ---------------- layernorm (bf16 in; bf16 or f32 out) ----------------
__device__ __forceinline__ float block_sum(float v, float* sbuf) {
#pragma unroll
  for (int off = 32; off > 0; off >>= 1) v += __shfl_xor(v, off, 64);
  int lane = threadIdx.x & 63, w = threadIdx.x >> 6;
  if (lane == 0) sbuf[w] = v;
  __syncthreads();
  v = sbuf[0] + sbuf[1] + sbuf[2] + sbuf[3];
  __syncthreads();
  return v;
}

template <bool OUT_BF16>
__global__ __launch_bounds__(256) void ln_kernel(
    const u16* __restrict__ x, const float* __restrict__ g,
    const float* __restrict__ b, void* __restrict__ out) {
  __shared__ float sbuf[4];
  int row = blockIdx.x, tid = threadIdx.x;
  const u16* xr = x + (size_t)row * D;
  float v0 = bf2f(xr[tid]), v1 = bf2f(xr[tid + 256]), v2 = bf2f(xr[tid + 512]);
  float s = block_sum(v0 + v1 + v2, sbuf);
  float mean = s * (1.0f / D);
  float d0 = v0 - mean, d1 = v1 - mean, d2 = v2 - mean;
  float sq = block_sum(d0 * d0 + d1 * d1 + d2 * d2, sbuf);
  float rs = rsqrtf(sq * (1.0f / D) + EPS_F);
  float y0 = d0 * rs * g[tid] + b[tid];
  float y1 = d1 * rs * g[tid + 256] + b[tid + 256];
  float y2 = d2 * rs * g[tid + 512] + b[tid + 512];
  if (OUT_BF16) {
    u16* o = (u16*)out + (size_t)row * D;
    o[tid] = f2bf(y0); o[tid + 256] = f2bf(y1); o[tid + 512] = f2bf(y2);
  } else {
    float* o = (float*)out + (size_t)row * D;
    o[tid] = y0; o[tid + 256] = y1; o[tid + 512] = y2;
  }
}

// ------------- ALL per-layer weight transposes+converts in ONE launch -------------
// blocks: [0,2304) Wq/Wk/Wv/Wo (576 each), [2304,2448) Wsim, [2448,4752) Wff1,
// [4752,7056) Wff2.  Each block: 32x32 transpose tile, W[Kd][N] f32 -> Wt[N][Kd] bf16.
struct WAll {
  const float *wq, *wk, *wv, *wo, *wsim, *wff1, *wff2;
  u16 *tA, *tB, *tC, *tD;
};
__global__ __launch_bounds__(256) void wconv_all_kernel(WAll p, float qscale) {
  __shared__ u16 t[32][33];
  int bid = blockIdx.x;
  const float* W; u16* Wt; int N, Kd, n0, k0;
  float sc = 1.0f;
  if (bid < 2304) {
    int z = bid / 576, rem = bid - z * 576;
    W = z == 0 ? p.wq : z == 1 ? p.wk : z == 2 ? p.wv : p.wo;
    Wt = z == 0 ? p.tA : z == 1 ? p.tA + 768 * 768
       : z == 2 ? p.tA + 2 * 768 * 768 : p.tB;
    if (z == 0) sc = qscale;
    N = 768; Kd = 768;
    n0 = (rem % 24) * 32; k0 = (rem / 24) * 32;
  } else if (bid < 2448) {
    int rem = bid - 2304;
    W = p.wsim; Wt = p.tA + (size_t)SIMOFF * 768; N = SIMC; Kd = 768;
    n0 = (rem % 6) * 32; k0 = (rem / 6) * 32;
  } else if (bid < 4752) {
    int rem = bid - 2448;
    W = p.wff1; Wt = p.tC; N = FFD; Kd = 768;
    n0 = (rem % 96) * 32; k0 = (rem / 96) * 32;
  } else {
    int rem = bid - 4752;
    W = p.wff2; Wt = p.tD; N = 768; Kd = FFD;
    n0 = (rem % 24) * 32; k0 = (rem / 24) * 32;
  }
  int tid = threadIdx.x;
  int c = tid & 31, r4 = tid >> 5;
#pragma unroll
  for (int i = 0; i < 4; ++i) {
    int r = r4 + i * 8;
    t[r][c] = f2bf(W[(size_t)(k0 + r) * N + n0 + c] * sc);
  }
  __syncthreads();
#pragma unroll
  for (int i = 0; i < 4; ++i) {
    int r = r4 + i * 8;
    Wt[(size_t)(n0 + r) * Kd + k0 + c] = t[c][r];
  }
}

// ===================== 256x256 8-phase GEMM (reads fused into MFMA region) ==========
// C[M,N] = A[M,K](bf16) @ Bt[N,K]^T(bf16).  512 thr = 8 waves (2M x 4N), BK=64,
// LDS 128KB = 2 K-tile buffers x (A,B). XOR swizzle (rule 21): pre-swizzled global
// source + swizzled ds_read, linear gload_lds dest.
// Phase = { stage issue ; ds_reads (ks0 then ks1) ; MFMA ; lgkmcnt(0)+[vmcnt] ; barrier }.
// Reads now live in the SAME barrier region as their consuming MFMA: the compiler
// emits counted lgkmcnt so MFMA-ks0 overlaps ks1's read latency. The trailing
// lgkmcnt(0)-before-barrier preserves the single-barrier invariant (all own LDS
// reads complete before any wave passes the barrier -> next phase's stages can't
// corrupt them). Stage/read ledger identical to the verified round-4/5 kernel:
// p4 vmcnt(4) retires {prev-t3B, t1A}; p8 vmcnt(4) retires {t2B, t2A}; reads of a
// buffer always sit AFTER the barrier that follows the vmcnt validating it.
// Last iter: p4 drains vmcnt(0); p5-p8 stage nothing.
template <bool OUT_BF16, bool BIAS, bool GELU_, bool RESID>
__global__ __launch_bounds__(512, 2) void gemm256_kernel(
    const u16* __restrict__ A, const u16* __restrict__ Bt,
    const float* __restrict__ bias, const u16* __restrict__ resid,
    void* __restrict__ Cout, int N, int Kdim, int NBX) {
  __shared__ u16 lds[65536];
  int tid = threadIdx.x;
  int w = tid >> 6, lane = tid & 63;
  int wm = w >> 2, wn = w & 3;
  int lr = lane & 15, lg = lane >> 4;

  int nwg = gridDim.x;
  int cpx = nwg >> 3;
  int swz = (blockIdx.x & 7) * cpx + (blockIdx.x >> 3);
  int bx = swz % NBX, by = swz / NBX;
  int n0 = bx << 8, m0 = by << 8;

  int scol = ((lane & 7) ^ (lane >> 3)) << 3;
  size_t aOff = (size_t)((w << 4) + (lane >> 3)) * Kdim + scol;
  u16* ldsU = lds;

  auto stageA = [&](int buf, int h, int t) {
    const u16* g = A + (size_t)(m0 + (h << 7)) * Kdim + ((size_t)t << 6) + aOff;
    u16* l = ldsU + buf * 32768 + h * 8192 + (w << 10);
    gload16(g, l);
    gload16(g + ((size_t)Kdim << 3), l + 512);
  };
  auto stageB = [&](int buf, int h, int t) {
    const u16* g = Bt + (size_t)(n0 + (h << 7)) * Kdim + ((size_t)t << 6) + aOff;
    u16* l = ldsU + buf * 32768 + 16384 + h * 8192 + (w << 10);
    gload16(g, l);
    gload16(g + ((size_t)Kdim << 3), l + 512);
  };

  const u16* lA0p = ldsU;
  const u16* lB0p = ldsU + 16384;
  const u16* lA1p = ldsU + 32768;
  const u16* lB1p = ldsU + 49152;
  int arow = (wm * 128 + lr) * 64;
  int brow = (wn * 64 + lr) * 64;
  int swz0 = (((lg * 16)) ^ ((lr & 7) << 4)) >> 1;
  int swz1 = ((64 + lg * 16) ^ ((lr & 7) << 4)) >> 1;

  f32x4 acc[8][4] = {};
  bf16x8 ar[2][4], br[2][4];

// ks-split reads: issue ks0 set first so MFMA-ks0's wait covers fewer loads.
#define READ_A_KS(BASE, MSEG, KS)                                            \
  do {                                                                       \
    _Pragma("unroll") for (int mm = 0; mm < 4; ++mm) {                       \
      const u16* p_ = (BASE) + arow + ((MSEG) * 64 + mm * 16) * 64;          \
      ar[KS][mm] = *(const bf16x8*)(p_ + ((KS) ? swz1 : swz0));              \
    }                                                                        \
  } while (0)
#define READ_B_KS(BASE, NSEG, KS)                                            \
  do {                                                                       \
    _Pragma("unroll") for (int nn = 0; nn < 2; ++nn) {                       \
      const u16* p_ = (BASE) + brow + ((NSEG) * 32 + nn * 16) * 64;          \
      br[KS][(NSEG) * 2 + nn] = *(const bf16x8*)(p_ + ((KS) ? swz1 : swz0)); \
    }                                                                        \
  } while (0)
#define MFMA_Q(MSEG, NSEG)                                                   \
  do {                                                                       \
    __builtin_amdgcn_s_setprio(1);                                           \
    _Pragma("unroll") for (int ks = 0; ks < 2; ++ks)                         \
      _Pragma("unroll") for (int mm = 0; mm < 4; ++mm)                       \
        _Pragma("unroll") for (int nn = 0; nn < 2; ++nn)                     \
          acc[(MSEG) * 4 + mm][(NSEG) * 2 + nn] =                            \
              __builtin_amdgcn_mfma_f32_16x16x32_bf16(                       \
                  ar[ks][mm], br[ks][(NSEG) * 2 + nn],                       \
                  acc[(MSEG) * 4 + mm][(NSEG) * 2 + nn], 0, 0, 0);           \
    __builtin_amdgcn_s_setprio(0);                                           \
  } while (0)
#define PSYNC()                                                              \
  do {                                                                       \
    __builtin_amdgcn_sched_barrier(0);                                       \
    asm volatile("s_waitcnt lgkmcnt(0)" ::: "memory");                       \
    __builtin_amdgcn_s_barrier();                                            \
    __builtin_amdgcn_sched_barrier(0);                                       \
  } while (0)
#define PSYNC_V(N)                                                           \
  do {                                                                       \
    __builtin_amdgcn_sched_barrier(0);                                       \
    asm volatile("s_waitcnt vmcnt(" #N ") lgkmcnt(0)" ::: "memory");         \
    __builtin_amdgcn_s_barrier();                                            \
    __builtin_amdgcn_sched_barrier(0);                                       \
  } while (0)

  int NK = Kdim >> 6, NI = NK >> 1;
  // ---- prologue: tile0 -> buf0 (4 halves), tile1 B -> buf1 ----
  stageA(0, 0, 0); stageA(0, 1, 0); stageB(0, 0, 0); stageB(0, 1, 0);
  stageB(1, 0, 1); stageB(1, 1, 1);
  asm volatile("s_waitcnt vmcnt(4)" ::: "memory");  // tile0 (oldest 8) landed
  __builtin_amdgcn_s_barrier();
  __builtin_amdgcn_sched_barrier(0);

  for (int i = 0; i < NI; ++i) {
    int t1 = 2 * i + 1, t2 = 2 * i + 2, t3 = 2 * i + 3;
    bool last = (i == NI - 1);
    // ---- p1 ----
    stageA(1, 0, t1);
    READ_A_KS(lA0p, 0, 0); READ_B_KS(lB0p, 0, 0);
    READ_A_KS(lA0p, 0, 1); READ_B_KS(lB0p, 0, 1);
    MFMA_Q(0, 0);
    PSYNC();
    // ---- p2 ----
    stageA(1, 1, t1);
    READ_B_KS(lB0p, 1, 0); READ_B_KS(lB0p, 1, 1);
    MFMA_Q(0, 1);
    PSYNC();
    // ---- p3 ----
    if (!last) stageB(0, 0, t2);
    READ_A_KS(lA0p, 1, 0); READ_A_KS(lA0p, 1, 1);
    MFMA_Q(1, 0);
    PSYNC();
    // ---- p4 ----
    if (!last) stageB(0, 1, t2);
    MFMA_Q(1, 1);
    if (last) PSYNC_V(0);
    else      PSYNC_V(4);
    // ---- p5 ----
    if (!last) stageA(0, 0, t2);
    READ_A_KS(lA1p, 0, 0); READ_B_KS(lB1p, 0, 0);
    READ_A_KS(lA1p, 0, 1); READ_B_KS(lB1p, 0, 1);
    MFMA_Q(0, 0);
    PSYNC();
    // ---- p6 ----
    if (!last) stageA(0, 1, t2);
    READ_B_KS(lB1p, 1, 0); READ_B_KS(lB1p, 1, 1);
    MFMA_Q(0, 1);
    PSYNC();
    // ---- p7 ----
    if (!last) stageB(1, 0, t3);
    READ_A_KS(lA1p, 1, 0); READ_A_KS(lA1p, 1, 1);
    MFMA_Q(1, 0);
    PSYNC();
    // ---- p8 ----
    if (!last) stageB(1, 1, t3);
    MFMA_Q(1, 1);
    if (last) PSYNC();
    else      PSYNC_V(4);
  }

  // ---- epilogue ----
#pragma unroll
  for (int m = 0; m < 8; ++m) {
#pragma unroll
    for (int n = 0; n < 4; ++n) {
      int col = n0 + wn * 64 + n * 16 + lr;
      float bv = BIAS ? bias[col] : 0.0f;
#pragma unroll
      for (int r = 0; r < 4; ++r) {
        int row = m0 + wm * 128 + m * 16 + lg * 4 + r;
        float v = acc[m][n][r];
        if (BIAS) v += bv;
        if (GELU_) v = fast_gelu(v);
        if (RESID) v += bf2f(resid[(size_t)row * N + col]);
        if (OUT_BF16) ((u16*)Cout)[(size_t)row * N + col] = f2bf(v);
        else ((float*)Cout)[(size_t)row * N + col] = v;
      }
    }
  }
#undef READ_A_KS
#undef READ_B_KS
#undef MFMA_Q
#undef PSYNC
#undef PSYNC_V
}

// --------- s-normalize: sbf = sqrt(BOOST*log2e) * s / max(||s||,1e-12) ---------
__global__ __launch_bounds__(64) void snorm_kernel(
    const u16* __restrict__ qkvb, u16* __restrict__ sbf) {
  int row = blockIdx.x, lane = threadIdx.x;
  const u16* sr = qkvb + (size_t)row * QKVW + SIMOFF;
  float v0 = bf2f(sr[lane]), v1 = bf2f(sr[lane + 64]), v2 = bf2f(sr[lane + 128]);
  float sq = v0 * v0 + v1 * v1 + v2 * v2;
#pragma unroll
  for (int off = 32; off > 0; off >>= 1) sq += __shfl_xor(sq, off, 64);
  float inv = SBOOST2 / fmaxf(sqrtf(sq), 1e-12f);
  u16* o = sbf + (size_t)row * SIMC;
  o[lane] = f2bf(v0 * inv);
  o[lane + 64] = f2bf(v1 * inv);
  o[lane + 128] = f2bf(v2 * inv);
}

// ---------------- MFMA attention: one block per (b,h), 4 waves x 32 q-rows ----------------
// scores(log2-domain) = (QSCALE*Q)K^T + sbf sbf^T ; softmax via exp2.
__global__ __launch_bounds__(256) void attn_kernel(
    const u16* __restrict__ qkv, const u16* __restrict__ sbf,
    u16* __restrict__ ob) {
  __shared__ u16 Vt[96][136];
  __shared__ u16 Pl[4][32][136];
  int bh = blockIdx.x, b = bh >> 3, h = bh & 7;
  int tid = threadIdx.x, w = tid >> 6, lane = tid & 63;
  int lr = lane & 15, lg = lane >> 4;
  const u16* qb = qkv + (size_t)b * K * QKVW + h * HD;
  const u16* kb = qb + D;
  const u16* vb = qb + 2 * D;
  const u16* sb = sbf + (size_t)b * K * SIMC;
  for (int idx = tid; idx < 128 * 12; idx += 256) {
    int r = idx / 12, db = idx - r * 12;
    uint4 v4 = *(const uint4*)(vb + (size_t)r * QKVW + db * 8);
    u32 vv[4] = {v4.x, v4.y, v4.z, v4.w};
#pragma unroll
    for (int j = 0; j < 4; ++j) {
      Vt[db * 8 + 2 * j][r] = (u16)(vv[j] & 0xffffu);
      Vt[db * 8 + 2 * j + 1][r] = (u16)(vv[j] >> 16);
    }
  }
  int q0 = 32 * w;
  f32x4 accs[2][8] = {};
#pragma unroll
  for (int ks = 0; ks < 3; ++ks) {
    bf16x8 af[2];
#pragma unroll
    for (int m = 0; m < 2; ++m)
      af[m] = *(const bf16x8*)(qb + (size_t)(q0 + 16 * m + lr) * QKVW + ks * 32 + lg * 8);
#pragma unroll
    for (int n = 0; n < 8; ++n) {
      bf16x8 bf = *(const bf16x8*)(kb + (size_t)(16 * n + lr) * QKVW + ks * 32 + lg * 8);
#pragma unroll
      for (int m = 0; m < 2; ++m)
        accs[m][n] = __builtin_amdgcn_mfma_f32_16x16x32_bf16(af[m], bf, accs[m][n], 0, 0, 0);
    }
  }
#pragma unroll
  for (int ks = 0; ks < 6; ++ks) {
    bf16x8 af[2];
#pragma unroll
    for (int m = 0; m < 2; ++m)
      af[m] = *(const bf16x8*)(sb + (size_t)(q0 + 16 * m + lr) * SIMC + ks * 32 + lg * 8);
#pragma unroll
    for (int n = 0; n < 8; ++n) {
      bf16x8 bf = *(const bf16x8*)(sb + (size_t)(16 * n + lr) * SIMC + ks * 32 + lg * 8);
#pragma unroll
      for (int m = 0; m < 2; ++m)
        accs[m][n] = __builtin_amdgcn_mfma_f32_16x16x32_bf16(af[m], bf, accs[m][n], 0, 0, 0);
    }
  }
#pragma unroll
  for (int m = 0; m < 2; ++m) {
    float mx[4] = {-3e38f, -3e38f, -3e38f, -3e38f};
#pragma unroll
    for (int n = 0; n < 8; ++n)
#pragma unroll
      for (int r = 0; r < 4; ++r) mx[r] = fmaxf(mx[r], accs[m][n][r]);
#pragma unroll
    for (int r = 0; r < 4; ++r) {
      mx[r] = fmaxf(mx[r], __shfl_xor(mx[r], 1, 64));
      mx[r] = fmaxf(mx[r], __shfl_xor(mx[r], 2, 64));
      mx[r] = fmaxf(mx[r], __shfl_xor(mx[r], 4, 64));
      mx[r] = fmaxf(mx[r], __shfl_xor(mx[r], 8, 64));
    }
    float sm[4] = {0.f, 0.f, 0.f, 0.f};
#pragma unroll
    for (int n = 0; n < 8; ++n)
#pragma unroll
      for (int r = 0; r < 4; ++r) {
        float e = __builtin_amdgcn_exp2f(accs[m][n][r] - mx[r]);
        accs[m][n][r] = e;
        sm[r] += e;
      }
#pragma unroll
    for (int r = 0; r < 4; ++r) {
      sm[r] += __shfl_xor(sm[r], 1, 64);
      sm[r] += __shfl_xor(sm[r], 2, 64);
      sm[r] += __shfl_xor(sm[r], 4, 64);
      sm[r] += __shfl_xor(sm[r], 8, 64);
    }
    float inv[4];
#pragma unroll
    for (int r = 0; r < 4; ++r) inv[r] = 1.0f / sm[r];
#pragma unroll
    for (int n = 0; n < 8; ++n)
#pragma unroll
      for (int r = 0; r < 4; ++r)
        Pl[w][16 * m + 4 * lg + r][16 * n + lr] = f2bf(accs[m][n][r] * inv[r]);
  }
  __syncthreads();
  f32x4 acco[2][6] = {};
#pragma unroll
  for (int ks = 0; ks < 4; ++ks) {
    bf16x8 pa[2];
#pragma unroll
    for (int m = 0; m < 2; ++m)
      pa[m] = *(const bf16x8*)(&Pl[w][16 * m + lr][ks * 32 + lg * 8]);
#pragma unroll
    for (int n = 0; n < 6; ++n) {
      bf16x8 bv = *(const bf16x8*)(&Vt[16 * n + lr][ks * 32 + lg * 8]);
#pragma unroll
      for (int m = 0; m < 2; ++m)
        acco[m][n] = __builtin_amdgcn_mfma_f32_16x16x32_bf16(pa[m], bv, acco[m][n], 0, 0, 0);
    }
  }
  u16* obb = ob + (size_t)b * K * D + h * HD;
#pragma unroll
  for (int m = 0; m < 2; ++m)
#pragma unroll
    for (int n = 0; n < 6; ++n)
#pragma unroll
      for (int r = 0; r < 4; ++r)
        obb[(size_t)(q0 + 16 * m + 4 * lg + r) * D + 16 * n + lr] = f2bf(acco[m][n][r]);
}

// ---------------- host ----------------
extern "C" void kernel_launch(void* const* d_in, const int* in_sizes, int n_in,
                              void* d_out, int out_size, void* d_ws, size_t ws_size,
                              hipStream_t stream) {
  (void)in_sizes; (void)n_in; (void)out_size;
  const float* slots = (const float*)d_in[0];
  const float* pos   = (const float*)d_in[1];
  const float* Wq    = (const float*)d_in[2];
  const float* Wk    = (const float*)d_in[3];
  const float* Wv    = (const float*)d_in[4];
  const float* Wo    = (const float*)d_in[5];
  const float* bo    = (const float*)d_in[6];
  const float* Wsim  = (const float*)d_in[7];
  const float* g1    = (const float*)d_in[8];
  const float* b1    = (const float*)d_in[9];
  const float* g2    = (const float*)d_in[10];
  const float* b2    = (const float*)d_in[11];
  const float* Wff1  = (const float*)d_in[12];
  const float* bff1  = (const float*)d_in[13];
  const float* Wff2  = (const float*)d_in[14];
  const float* bff2  = (const float*)d_in[15];
  const float* gf    = (const float*)d_in[16];
  const float* bfin  = (const float*)d_in[17];

  char* p = (char*)d_ws;
  u16*   x    = (u16*)p;   p += (size_t)M * D * 2;        // 25.2 MB (bf16 residual)
  u16*   nx   = (u16*)p;   p += (size_t)M * D * 2;        // 25.2 MB
  u16*   qkvb = (u16*)p;   p += (size_t)M * QKVW * 2;     // 83.9 MB
  u16*   ob   = (u16*)p;   p += (size_t)M * D * 2;        // 25.2 MB
  u16*   sbf  = (u16*)p;   p += (size_t)M * SIMC * 2;     // 6.3 MB
  u16*   wtA  = (u16*)p;   p += (size_t)QKVW * D * 2;     // 3.9 MB (qkv + sim + pad)
  u16*   wtB  = (u16*)p;   p += (size_t)D * D * 2;        // 1.2 MB
  u16*   wtC  = (u16*)p;   p += (size_t)FFD * D * 2;      // 4.7 MB
  u16*   wtD  = (u16*)p;   p += (size_t)D * FFD * 2;      // 4.7 MB
  if ((size_t)(p - (char*)d_ws) > ws_size) return;
  u16* hb = qkvb;  // [M][3072] ffn hidden (spans qkvb+ob = 109 MB >= 100.7 MB)

  // zero the 64 pad rows of wtA once per call (never overwritten by wconvs)
  hipMemsetAsync(wtA + (size_t)(SIMOFF + SIMC) * D, 0, (size_t)64 * D * 2, stream);

  addpos_kernel<<<M * D / 256, 256, 0, stream>>>(slots, pos, x);

  int nbx_qkv = QKVW / 256, nwg_qkv = nbx_qkv * (M / 256);  // 10 x 64 = 640
  int nbx_o   = D / 256,    nwg_o   = nbx_o * (M / 256);    // 3 x 64 = 192
  int nbx_f1  = FFD / 256,  nwg_f1  = nbx_f1 * (M / 256);   // 12 x 64 = 768

  for (int l = 0; l < NL; ++l) {
    ln_kernel<true><<<M, 256, 0, stream>>>(x, g1 + l * D, b1 + l * D, nx);
    WAll wp = {Wq + (size_t)l * D * D, Wk + (size_t)l * D * D,
               Wv + (size_t)l * D * D, Wo + (size_t)l * D * D,
               Wsim + (size_t)l * D * SIMC,
               Wff1 + (size_t)l * D * FFD, Wff2 + (size_t)l * FFD * D,
               wtA, wtB, wtC, wtD};
    wconv_all_kernel<<<7056, 256, 0, stream>>>(wp, QSCALE);
    gemm256_kernel<true, false, false, false><<<nwg_qkv, 512, 0, stream>>>(
        nx, wtA, nullptr, nullptr, qkvb, QKVW, D, nbx_qkv);
    snorm_kernel<<<M, 64, 0, stream>>>(qkvb, sbf);
    attn_kernel<<<B * NH, 256, 0, stream>>>(qkvb, sbf, ob);
    gemm256_kernel<true, true, false, true><<<nwg_o, 512, 0, stream>>>(
        ob, wtB, bo + l * D, x, x, D, D, nbx_o);
    ln_kernel<true><<<M, 256, 0, stream>>>(x, g2 + l * D, b2 + l * D, nx);
    gemm256_kernel<true, true, true, false><<<nwg_f1, 512, 0, stream>>>(
        nx, wtC, bff1 + l * FFD, nullptr, hb, FFD, D, nbx_f1);
    gemm256_kernel<true, true, false, true><<<nwg_o, 512, 0, stream>>>(
        hb, wtD, bff2 + l * D, x, x, D, FFD, nbx_o);
  }
  ln_kernel<false><<<M, 256, 0, stream>>>(x, gf, bfin, d_out);
}

// Round 7
// 1402.088 us; speedup vs baseline: 6.1624x; 1.0756x over previous
//
#include <hip/hip_runtime.h>

typedef unsigned short u16;
typedef unsigned int u32;
typedef float f32x4 __attribute__((ext_vector_type(4)));
typedef __bf16 bf16x8 __attribute__((ext_vector_type(8)));

static constexpr int D = 768, FFD = 3072, SIMC = 192, NH = 8, HD = 96;
static constexpr int B = 128, K = 128, M = B * K, NL = 4;
static constexpr int QKVW = 2560;   // q(768) k(768) v(768) s(192) pad(64)
static constexpr int SIMOFF = 2304;
// Q pre-scale = HD^-0.5 * log2(e)  (softmax runs in exp2 domain)
static constexpr float QSCALE = 0.14724502f;
// s pre-scale = sqrt(BOOST * log2(e))
static constexpr float SBOOST2 = 0.6578821f;
static constexpr float EPS_F = 1e-5f;

__device__ __forceinline__ float bf2f(u16 u) {
  union { u32 i; float f; } v; v.i = ((u32)u) << 16; return v.f;
}
__device__ __forceinline__ u16 f2bf(float f) {
  union { float f; u32 i; } v; v.f = f;
  u32 u = v.i;
  u32 r = (u + 0x7FFFu + ((u >> 16) & 1u)) >> 16;
  return (u16)r;
}

// tanh-form GELU via v_exp_f32/v_rcp_f32; max |err| vs erf-GELU ~3e-3.
__device__ __forceinline__ float fast_gelu(float x) {
  float u2 = x * (2.3020585f + 0.102944f * x * x);
  float e = __builtin_amdgcn_exp2f(u2);
  float r = __builtin_amdgcn_rcpf(1.0f + e);
  return x - x * r;
}

__device__ __forceinline__ void gload16(const void* g, void* l) {
  __builtin_amdgcn_global_load_lds(
      (const __attribute__((address_space(1))) void*)g,
      (__attribute__((address_space(3))) void*)l, 16, 0, 0);
}

// ---------------- add positional embedding (x is bf16 residual stream) ----------------
__global__ __launch_bounds__(256) void addpos_kernel(
    const float* __restrict__ slots, const float* __restrict__ pos,
    u16* __restrict__ x) {
  int i = blockIdx.x * 256 + threadIdx.x;
  int m = i / D;
  int d = i - m * D;
  x[i] = f2bf(slots[i] + pos[(m & (K - 1)) * D + d]);
}

// ---------------- layernorm (bf16 in; bf16 or f32 out) ----------------
__device__ __forceinline__ float block_sum(float v, float* sbuf) {
#pragma unroll
  for (int off = 32; off > 0; off >>= 1) v += __shfl_xor(v, off, 64);
  int lane = threadIdx.x & 63, w = threadIdx.x >> 6;
  if (lane == 0) sbuf[w] = v;
  __syncthreads();
  v = sbuf[0] + sbuf[1] + sbuf[2] + sbuf[3];
  __syncthreads();
  return v;
}

template <bool OUT_BF16>
__global__ __launch_bounds__(256) void ln_kernel(
    const u16* __restrict__ x, const float* __restrict__ g,
    const float* __restrict__ b, void* __restrict__ out) {
  __shared__ float sbuf[4];
  int row = blockIdx.x, tid = threadIdx.x;
  const u16* xr = x + (size_t)row * D;
  float v0 = bf2f(xr[tid]), v1 = bf2f(xr[tid + 256]), v2 = bf2f(xr[tid + 512]);
  float s = block_sum(v0 + v1 + v2, sbuf);
  float mean = s * (1.0f / D);
  float d0 = v0 - mean, d1 = v1 - mean, d2 = v2 - mean;
  float sq = block_sum(d0 * d0 + d1 * d1 + d2 * d2, sbuf);
  float rs = rsqrtf(sq * (1.0f / D) + EPS_F);
  float y0 = d0 * rs * g[tid] + b[tid];
  float y1 = d1 * rs * g[tid + 256] + b[tid + 256];
  float y2 = d2 * rs * g[tid + 512] + b[tid + 512];
  if (OUT_BF16) {
    u16* o = (u16*)out + (size_t)row * D;
    o[tid] = f2bf(y0); o[tid + 256] = f2bf(y1); o[tid + 512] = f2bf(y2);
  } else {
    float* o = (float*)out + (size_t)row * D;
    o[tid] = y0; o[tid + 256] = y1; o[tid + 512] = y2;
  }
}

// ------------- ALL per-layer weight transposes+converts in ONE launch -------------
struct WAll {
  const float *wq, *wk, *wv, *wo, *wsim, *wff1, *wff2;
  u16 *tA, *tB, *tC, *tD;
};
__global__ __launch_bounds__(256) void wconv_all_kernel(WAll p, float qscale) {
  __shared__ u16 t[32][33];
  int bid = blockIdx.x;
  const float* W; u16* Wt; int N, Kd, n0, k0;
  float sc = 1.0f;
  if (bid < 2304) {
    int z = bid / 576, rem = bid - z * 576;
    W = z == 0 ? p.wq : z == 1 ? p.wk : z == 2 ? p.wv : p.wo;
    Wt = z == 0 ? p.tA : z == 1 ? p.tA + 768 * 768
       : z == 2 ? p.tA + 2 * 768 * 768 : p.tB;
    if (z == 0) sc = qscale;
    N = 768; Kd = 768;
    n0 = (rem % 24) * 32; k0 = (rem / 24) * 32;
  } else if (bid < 2448) {
    int rem = bid - 2304;
    W = p.wsim; Wt = p.tA + (size_t)SIMOFF * 768; N = SIMC; Kd = 768;
    n0 = (rem % 6) * 32; k0 = (rem / 6) * 32;
  } else if (bid < 4752) {
    int rem = bid - 2448;
    W = p.wff1; Wt = p.tC; N = FFD; Kd = 768;
    n0 = (rem % 96) * 32; k0 = (rem / 96) * 32;
  } else {
    int rem = bid - 4752;
    W = p.wff2; Wt = p.tD; N = 768; Kd = FFD;
    n0 = (rem % 24) * 32; k0 = (rem / 24) * 32;
  }
  int tid = threadIdx.x;
  int c = tid & 31, r4 = tid >> 5;
#pragma unroll
  for (int i = 0; i < 4; ++i) {
    int r = r4 + i * 8;
    t[r][c] = f2bf(W[(size_t)(k0 + r) * N + n0 + c] * sc);
  }
  __syncthreads();
#pragma unroll
  for (int i = 0; i < 4; ++i) {
    int r = r4 + i * 8;
    Wt[(size_t)(n0 + r) * Kd + k0 + c] = t[c][r];
  }
}

// ===================== 256x256 6-phase GEMM =====================
// C[M,N] = A[M,K](bf16) @ Bt[N,K]^T(bf16).  512 thr = 8 waves (2M x 4N), BK=64,
// LDS 128KB = 2 K-tile dbuf x (A,B). XOR swizzle (rule 21): pre-swizzled global
// source + swizzled ds_read, linear gload_lds dest.
// 6 phases / 2 K-tiles:
//  q1{stageA(1,0,t1); read A0,B0(buf0); MFMA(0,0)}  q2{stageA(1,1,t1); read B1; MFMA(0,1)}
//  q3{stageB(0,0/1,t2); read A1; MFMA(1,0)+(1,1); vmcnt(4)}
//  q4{stageA(0,0,t2); read A0,B0(buf1); MFMA(0,0)}  q5{stageA(0,1,t2); read B1; MFMA(0,1)}
//  q6{stageB(1,0/1,t3); read A1; MFMA(1,0)+(1,1); vmcnt(4)}
// Ledger (steady): entering iter in-flight = {t1.B:4}. q1+2,q2+2,q3+4 -> 12;
// vmcnt(4) retires oldest 8 = t1.{B,A} (read by q4-q6) -> ok. q4+2,q5+2,q6+4
// -> 12; vmcnt(4) retires t2.{B,A} (read by next q1-q3) -> ok. Stage targets
// always last-read >=1 barrier earlier. Last iter: q3 drains vmcnt(0), q6 PSYNC.
template <bool OUT_BF16, bool BIAS, bool GELU_, bool RESID>
__global__ __launch_bounds__(512, 2) void gemm256_kernel(
    const u16* __restrict__ A, const u16* __restrict__ Bt,
    const float* __restrict__ bias, const u16* __restrict__ resid,
    void* __restrict__ Cout, int N, int Kdim, int NBX) {
  __shared__ u16 lds[65536];
  int tid = threadIdx.x;
  int w = tid >> 6, lane = tid & 63;
  int wm = w >> 2, wn = w & 3;
  int lr = lane & 15, lg = lane >> 4;

  int nwg = gridDim.x;
  int cpx = nwg >> 3;
  int swz = (blockIdx.x & 7) * cpx + (blockIdx.x >> 3);
  int bx = swz % NBX, by = swz / NBX;
  int n0 = bx << 8, m0 = by << 8;

  int scol = ((lane & 7) ^ (lane >> 3)) << 3;
  size_t aOff = (size_t)((w << 4) + (lane >> 3)) * Kdim + scol;
  u16* ldsU = lds;

  auto stageA = [&](int buf, int h, int t) {
    const u16* g = A + (size_t)(m0 + (h << 7)) * Kdim + ((size_t)t << 6) + aOff;
    u16* l = ldsU + buf * 32768 + h * 8192 + (w << 10);
    gload16(g, l);
    gload16(g + ((size_t)Kdim << 3), l + 512);
  };
  auto stageB = [&](int buf, int h, int t) {
    const u16* g = Bt + (size_t)(n0 + (h << 7)) * Kdim + ((size_t)t << 6) + aOff;
    u16* l = ldsU + buf * 32768 + 16384 + h * 8192 + (w << 10);
    gload16(g, l);
    gload16(g + ((size_t)Kdim << 3), l + 512);
  };

  const u16* lA0p = ldsU;
  const u16* lB0p = ldsU + 16384;
  const u16* lA1p = ldsU + 32768;
  const u16* lB1p = ldsU + 49152;
  int arow = (wm * 128 + lr) * 64;
  int brow = (wn * 64 + lr) * 64;
  int swz0 = (((lg * 16)) ^ ((lr & 7) << 4)) >> 1;
  int swz1 = ((64 + lg * 16) ^ ((lr & 7) << 4)) >> 1;

  f32x4 acc[8][4] = {};
  bf16x8 ar[2][4], br[2][4];

#define READ_A_KS(BASE, MSEG, KS)                                            \
  do {                                                                       \
    _Pragma("unroll") for (int mm = 0; mm < 4; ++mm) {                       \
      const u16* p_ = (BASE) + arow + ((MSEG) * 64 + mm * 16) * 64;          \
      ar[KS][mm] = *(const bf16x8*)(p_ + ((KS) ? swz1 : swz0));              \
    }                                                                        \
  } while (0)
#define READ_B_KS(BASE, NSEG, KS)                                            \
  do {                                                                       \
    _Pragma("unroll") for (int nn = 0; nn < 2; ++nn) {                       \
      const u16* p_ = (BASE) + brow + ((NSEG) * 32 + nn * 16) * 64;          \
      br[KS][(NSEG) * 2 + nn] = *(const bf16x8*)(p_ + ((KS) ? swz1 : swz0)); \
    }                                                                        \
  } while (0)
#define MFMA_Q(MSEG, NSEG)                                                   \
  do {                                                                       \
    __builtin_amdgcn_s_setprio(1);                                           \
    _Pragma("unroll") for (int ks = 0; ks < 2; ++ks)                         \
      _Pragma("unroll") for (int mm = 0; mm < 4; ++mm)                       \
        _Pragma("unroll") for (int nn = 0; nn < 2; ++nn)                     \
          acc[(MSEG) * 4 + mm][(NSEG) * 2 + nn] =                            \
              __builtin_amdgcn_mfma_f32_16x16x32_bf16(                       \
                  ar[ks][mm], br[ks][(NSEG) * 2 + nn],                       \
                  acc[(MSEG) * 4 + mm][(NSEG) * 2 + nn], 0, 0, 0);           \
    __builtin_amdgcn_s_setprio(0);                                           \
  } while (0)
#define PSYNC()                                                              \
  do {                                                                       \
    __builtin_amdgcn_sched_barrier(0);                                       \
    asm volatile("s_waitcnt lgkmcnt(0)" ::: "memory");                       \
    __builtin_amdgcn_s_barrier();                                            \
    __builtin_amdgcn_sched_barrier(0);                                       \
  } while (0)
#define PSYNC_V(N)                                                           \
  do {                                                                       \
    __builtin_amdgcn_sched_barrier(0);                                       \
    asm volatile("s_waitcnt vmcnt(" #N ") lgkmcnt(0)" ::: "memory");         \
    __builtin_amdgcn_s_barrier();                                            \
    __builtin_amdgcn_sched_barrier(0);                                       \
  } while (0)

  int NK = Kdim >> 6, NI = NK >> 1;
  // prologue: tile0 -> buf0 (4 halves), tile1 B -> buf1
  stageA(0, 0, 0); stageA(0, 1, 0); stageB(0, 0, 0); stageB(0, 1, 0);
  stageB(1, 0, 1); stageB(1, 1, 1);
  asm volatile("s_waitcnt vmcnt(4)" ::: "memory");
  __builtin_amdgcn_s_barrier();
  __builtin_amdgcn_sched_barrier(0);

  for (int i = 0; i < NI; ++i) {
    int t1 = 2 * i + 1, t2 = 2 * i + 2, t3 = 2 * i + 3;
    bool last = (i == NI - 1);
    // ---- q1 ----
    stageA(1, 0, t1);
    READ_A_KS(lA0p, 0, 0); READ_B_KS(lB0p, 0, 0);
    READ_A_KS(lA0p, 0, 1); READ_B_KS(lB0p, 0, 1);
    MFMA_Q(0, 0);
    PSYNC();
    // ---- q2 ----
    stageA(1, 1, t1);
    READ_B_KS(lB0p, 1, 0); READ_B_KS(lB0p, 1, 1);
    MFMA_Q(0, 1);
    PSYNC();
    // ---- q3 ----
    if (!last) { stageB(0, 0, t2); stageB(0, 1, t2); }
    READ_A_KS(lA0p, 1, 0); READ_A_KS(lA0p, 1, 1);
    MFMA_Q(1, 0); MFMA_Q(1, 1);
    if (last) PSYNC_V(0);
    else      PSYNC_V(4);
    // ---- q4 ----
    if (!last) stageA(0, 0, t2);
    READ_A_KS(lA1p, 0, 0); READ_B_KS(lB1p, 0, 0);
    READ_A_KS(lA1p, 0, 1); READ_B_KS(lB1p, 0, 1);
    MFMA_Q(0, 0);
    PSYNC();
    // ---- q5 ----
    if (!last) stageA(0, 1, t2);
    READ_B_KS(lB1p, 1, 0); READ_B_KS(lB1p, 1, 1);
    MFMA_Q(0, 1);
    PSYNC();
    // ---- q6 ----
    if (!last) { stageB(1, 0, t3); stageB(1, 1, t3); }
    READ_A_KS(lA1p, 1, 0); READ_A_KS(lA1p, 1, 1);
    MFMA_Q(1, 0); MFMA_Q(1, 1);
    if (last) PSYNC();
    else      PSYNC_V(4);
  }

  // ---- epilogue ----
#pragma unroll
  for (int m = 0; m < 8; ++m) {
#pragma unroll
    for (int n = 0; n < 4; ++n) {
      int col = n0 + wn * 64 + n * 16 + lr;
      float bv = BIAS ? bias[col] : 0.0f;
#pragma unroll
      for (int r = 0; r < 4; ++r) {
        int row = m0 + wm * 128 + m * 16 + lg * 4 + r;
        float v = acc[m][n][r];
        if (BIAS) v += bv;
        if (GELU_) v = fast_gelu(v);
        if (RESID) v += bf2f(resid[(size_t)row * N + col]);
        if (OUT_BF16) ((u16*)Cout)[(size_t)row * N + col] = f2bf(v);
        else ((float*)Cout)[(size_t)row * N + col] = v;
      }
    }
  }
#undef READ_A_KS
#undef READ_B_KS
#undef MFMA_Q
#undef PSYNC
#undef PSYNC_V
}

// --------- per-batch sim precompute: psim[b] = (norm(s_b)*SBOOST2)(...)^T ---------
// One block per batch. Normalizes s rows in LDS (replaces snorm_kernel), then
// 4 waves x 32 q-rows MFMA s.s^T, writes bf16 [128][128].
__global__ __launch_bounds__(256) void simpre_kernel(
    const u16* __restrict__ qkvb, u16* __restrict__ psim) {
  __shared__ u16 sln[128][200];  // normalized s, +8 pad (2-way bank: free)
  int b = blockIdx.x, tid = threadIdx.x;
  {
    int row = tid >> 1, half = tid & 1;
    const u16* sr = qkvb + ((size_t)(b * K + row)) * QKVW + SIMOFF + half * 96;
    u16 v[96];
    float sq = 0.f;
#pragma unroll
    for (int j = 0; j < 12; ++j) {
      uint4 u4 = *(const uint4*)(sr + j * 8);
      u32 uu[4] = {u4.x, u4.y, u4.z, u4.w};
#pragma unroll
      for (int t = 0; t < 4; ++t) {
        v[j * 8 + 2 * t] = (u16)(uu[t] & 0xffffu);
        v[j * 8 + 2 * t + 1] = (u16)(uu[t] >> 16);
      }
    }
#pragma unroll
    for (int j = 0; j < 96; ++j) { float f = bf2f(v[j]); sq += f * f; }
    sq += __shfl_xor(sq, 1, 64);
    float inv = SBOOST2 / fmaxf(sqrtf(sq), 1e-12f);
#pragma unroll
    for (int j = 0; j < 96; ++j) sln[row][half * 96 + j] = f2bf(bf2f(v[j]) * inv);
  }
  __syncthreads();
  int w = tid >> 6, lane = tid & 63;
  int lr = lane & 15, lg = lane >> 4;
  int q0 = 32 * w;
  f32x4 accs[2][8] = {};
#pragma unroll
  for (int ks = 0; ks < 6; ++ks) {
    bf16x8 af[2];
#pragma unroll
    for (int m = 0; m < 2; ++m)
      af[m] = *(const bf16x8*)(&sln[q0 + 16 * m + lr][ks * 32 + lg * 8]);
#pragma unroll
    for (int n = 0; n < 8; ++n) {
      bf16x8 bf = *(const bf16x8*)(&sln[16 * n + lr][ks * 32 + lg * 8]);
#pragma unroll
      for (int m = 0; m < 2; ++m)
        accs[m][n] = __builtin_amdgcn_mfma_f32_16x16x32_bf16(af[m], bf, accs[m][n], 0, 0, 0);
    }
  }
  u16* pb = psim + (size_t)b * K * K;
#pragma unroll
  for (int m = 0; m < 2; ++m)
#pragma unroll
    for (int n = 0; n < 8; ++n)
#pragma unroll
      for (int r = 0; r < 4; ++r)
        pb[(size_t)(q0 + 16 * m + 4 * lg + r) * K + 16 * n + lr] = f2bf(accs[m][n][r]);
}

// ---------------- MFMA attention: one block per (b,h), 4 waves x 32 q-rows ----------------
// scores(log2-domain) init from psim tile, + (QSCALE*Q)K^T ; softmax via exp2.
__global__ __launch_bounds__(256) void attn_kernel(
    const u16* __restrict__ qkv, const u16* __restrict__ psim,
    u16* __restrict__ ob) {
  __shared__ u16 Vt[96][136];
  __shared__ u16 Pl[4][32][136];
  int bh = blockIdx.x, b = bh >> 3, h = bh & 7;
  int tid = threadIdx.x, w = tid >> 6, lane = tid & 63;
  int lr = lane & 15, lg = lane >> 4;
  const u16* qb = qkv + (size_t)b * K * QKVW + h * HD;
  const u16* kb = qb + D;
  const u16* vb = qb + 2 * D;
  // stage V transposed
  for (int idx = tid; idx < 128 * 12; idx += 256) {
    int r = idx / 12, db = idx - r * 12;
    uint4 v4 = *(const uint4*)(vb + (size_t)r * QKVW + db * 8);
    u32 vv[4] = {v4.x, v4.y, v4.z, v4.w};
#pragma unroll
    for (int j = 0; j < 4; ++j) {
      Vt[db * 8 + 2 * j][r] = (u16)(vv[j] & 0xffffu);
      Vt[db * 8 + 2 * j + 1][r] = (u16)(vv[j] >> 16);
    }
  }
  // stage sim tile into the Pl region ([128][136] view); each wave later
  // reads/overwrites only its own 32 rows (wave-local after the sync).
  u16* siml = &Pl[0][0][0];
  {
    const u16* pb = psim + (size_t)b * K * K;
    for (int c = tid; c < 2048; c += 256) {
      int r = c >> 4, cc = c & 15;
      *(uint4*)(siml + r * 136 + cc * 8) = *(const uint4*)(pb + r * 128 + cc * 8);
    }
  }
  __syncthreads();
  int q0 = 32 * w;
  // acc init from sim (C/D fragment layout: row=16m+4lg+r, col=16n+lr)
  f32x4 accs[2][8];
#pragma unroll
  for (int m = 0; m < 2; ++m)
#pragma unroll
    for (int n = 0; n < 8; ++n)
#pragma unroll
      for (int r = 0; r < 4; ++r)
        accs[m][n][r] = bf2f(siml[(q0 + 16 * m + 4 * lg + r) * 136 + 16 * n + lr]);
  // QK^T
#pragma unroll
  for (int ks = 0; ks < 3; ++ks) {
    bf16x8 af[2];
#pragma unroll
    for (int m = 0; m < 2; ++m)
      af[m] = *(const bf16x8*)(qb + (size_t)(q0 + 16 * m + lr) * QKVW + ks * 32 + lg * 8);
#pragma unroll
    for (int n = 0; n < 8; ++n) {
      bf16x8 bf = *(const bf16x8*)(kb + (size_t)(16 * n + lr) * QKVW + ks * 32 + lg * 8);
#pragma unroll
      for (int m = 0; m < 2; ++m)
        accs[m][n] = __builtin_amdgcn_mfma_f32_16x16x32_bf16(af[m], bf, accs[m][n], 0, 0, 0);
    }
  }
  // softmax (exp2 domain) + write P
#pragma unroll
  for (int m = 0; m < 2; ++m) {
    float mx[4] = {-3e38f, -3e38f, -3e38f, -3e38f};
#pragma unroll
    for (int n = 0; n < 8; ++n)
#pragma unroll
      for (int r = 0; r < 4; ++r) mx[r] = fmaxf(mx[r], accs[m][n][r]);
#pragma unroll
    for (int r = 0; r < 4; ++r) {
      mx[r] = fmaxf(mx[r], __shfl_xor(mx[r], 1, 64));
      mx[r] = fmaxf(mx[r], __shfl_xor(mx[r], 2, 64));
      mx[r] = fmaxf(mx[r], __shfl_xor(mx[r], 4, 64));
      mx[r] = fmaxf(mx[r], __shfl_xor(mx[r], 8, 64));
    }
    float sm[4] = {0.f, 0.f, 0.f, 0.f};
#pragma unroll
    for (int n = 0; n < 8; ++n)
#pragma unroll
      for (int r = 0; r < 4; ++r) {
        float e = __builtin_amdgcn_exp2f(accs[m][n][r] - mx[r]);
        accs[m][n][r] = e;
        sm[r] += e;
      }
#pragma unroll
    for (int r = 0; r < 4; ++r) {
      sm[r] += __shfl_xor(sm[r], 1, 64);
      sm[r] += __shfl_xor(sm[r], 2, 64);
      sm[r] += __shfl_xor(sm[r], 4, 64);
      sm[r] += __shfl_xor(sm[r], 8, 64);
    }
    float inv[4];
#pragma unroll
    for (int r = 0; r < 4; ++r) inv[r] = 1.0f / sm[r];
#pragma unroll
    for (int n = 0; n < 8; ++n)
#pragma unroll
      for (int r = 0; r < 4; ++r)
        Pl[w][16 * m + 4 * lg + r][16 * n + lr] = f2bf(accs[m][n][r] * inv[r]);
  }
  __syncthreads();
  // PV
  f32x4 acco[2][6] = {};
#pragma unroll
  for (int ks = 0; ks < 4; ++ks) {
    bf16x8 pa[2];
#pragma unroll
    for (int m = 0; m < 2; ++m)
      pa[m] = *(const bf16x8*)(&Pl[w][16 * m + lr][ks * 32 + lg * 8]);
#pragma unroll
    for (int n = 0; n < 6; ++n) {
      bf16x8 bv = *(const bf16x8*)(&Vt[16 * n + lr][ks * 32 + lg * 8]);
#pragma unroll
      for (int m = 0; m < 2; ++m)
        acco[m][n] = __builtin_amdgcn_mfma_f32_16x16x32_bf16(pa[m], bv, acco[m][n], 0, 0, 0);
    }
  }
  u16* obb = ob + (size_t)b * K * D + h * HD;
#pragma unroll
  for (int m = 0; m < 2; ++m)
#pragma unroll
    for (int n = 0; n < 6; ++n)
#pragma unroll
      for (int r = 0; r < 4; ++r)
        obb[(size_t)(q0 + 16 * m + 4 * lg + r) * D + 16 * n + lr] = f2bf(acco[m][n][r]);
}

// ---------------- host ----------------
extern "C" void kernel_launch(void* const* d_in, const int* in_sizes, int n_in,
                              void* d_out, int out_size, void* d_ws, size_t ws_size,
                              hipStream_t stream) {
  (void)in_sizes; (void)n_in; (void)out_size;
  const float* slots = (const float*)d_in[0];
  const float* pos   = (const float*)d_in[1];
  const float* Wq    = (const float*)d_in[2];
  const float* Wk    = (const float*)d_in[3];
  const float* Wv    = (const float*)d_in[4];
  const float* Wo    = (const float*)d_in[5];
  const float* bo    = (const float*)d_in[6];
  const float* Wsim  = (const float*)d_in[7];
  const float* g1    = (const float*)d_in[8];
  const float* b1    = (const float*)d_in[9];
  const float* g2    = (const float*)d_in[10];
  const float* b2    = (const float*)d_in[11];
  const float* Wff1  = (const float*)d_in[12];
  const float* bff1  = (const float*)d_in[13];
  const float* Wff2  = (const float*)d_in[14];
  const float* bff2  = (const float*)d_in[15];
  const float* gf    = (const float*)d_in[16];
  const float* bfin  = (const float*)d_in[17];

  char* p = (char*)d_ws;
  u16*   x    = (u16*)p;   p += (size_t)M * D * 2;        // 25.2 MB (bf16 residual)
  u16*   nx   = (u16*)p;   p += (size_t)M * D * 2;        // 25.2 MB
  u16*   qkvb = (u16*)p;   p += (size_t)M * QKVW * 2;     // 83.9 MB
  u16*   ob   = (u16*)p;   p += (size_t)M * D * 2;        // 25.2 MB
  u16*   psim = (u16*)p;   p += (size_t)B * K * K * 2;    // 4.2 MB
  u16*   wtA  = (u16*)p;   p += (size_t)QKVW * D * 2;     // 3.9 MB (qkv + sim + pad)
  u16*   wtB  = (u16*)p;   p += (size_t)D * D * 2;        // 1.2 MB
  u16*   wtC  = (u16*)p;   p += (size_t)FFD * D * 2;      // 4.7 MB
  u16*   wtD  = (u16*)p;   p += (size_t)D * FFD * 2;      // 4.7 MB
  if ((size_t)(p - (char*)d_ws) > ws_size) return;
  u16* hb = qkvb;  // [M][3072] ffn hidden (spans qkvb+ob = 109 MB >= 100.7 MB)

  addpos_kernel<<<M * D / 256, 256, 0, stream>>>(slots, pos, x);

  int nbx_qkv = QKVW / 256, nwg_qkv = nbx_qkv * (M / 256);  // 10 x 64 = 640
  int nbx_o   = D / 256,    nwg_o   = nbx_o * (M / 256);    // 3 x 64 = 192
  int nbx_f1  = FFD / 256,  nwg_f1  = nbx_f1 * (M / 256);   // 12 x 64 = 768

  for (int l = 0; l < NL; ++l) {
    ln_kernel<true><<<M, 256, 0, stream>>>(x, g1 + l * D, b1 + l * D, nx);
    WAll wp = {Wq + (size_t)l * D * D, Wk + (size_t)l * D * D,
               Wv + (size_t)l * D * D, Wo + (size_t)l * D * D,
               Wsim + (size_t)l * D * SIMC,
               Wff1 + (size_t)l * D * FFD, Wff2 + (size_t)l * FFD * D,
               wtA, wtB, wtC, wtD};
    wconv_all_kernel<<<7056, 256, 0, stream>>>(wp, QSCALE);
    gemm256_kernel<true, false, false, false><<<nwg_qkv, 512, 0, stream>>>(
        nx, wtA, nullptr, nullptr, qkvb, QKVW, D, nbx_qkv);
    simpre_kernel<<<B, 256, 0, stream>>>(qkvb, psim);
    attn_kernel<<<B * NH, 256, 0, stream>>>(qkvb, psim, ob);
    gemm256_kernel<true, true, false, true><<<nwg_o, 512, 0, stream>>>(
        ob, wtB, bo + l * D, x, x, D, D, nbx_o);
    ln_kernel<true><<<M, 256, 0, stream>>>(x, g2 + l * D, b2 + l * D, nx);
    gemm256_kernel<true, true, true, false><<<nwg_f1, 512, 0, stream>>>(
        nx, wtC, bff1 + l * FFD, nullptr, hb, FFD, D, nbx_f1);
    gemm256_kernel<true, true, false, true><<<nwg_o, 512, 0, stream>>>(
        hb, wtD, bff2 + l * D, x, x, D, FFD, nbx_o);
  }
  ln_kernel<false><<<M, 256, 0, stream>>>(x, gf, bfin, d_out);
}